// Round 3
// baseline (179.848 us; speedup 1.0000x reference)
//
#include <hip/hip_runtime.h>

// Attention_73375221285454: fused MHA block on MI355X (gfx950)
// B=4 N=2048 D=768 H=12 DH=64. fp32 in/out, bf16 MFMA internally.
// Round 3: k-mask as MFMA bias column, q-mask via Vmean epilogue substitute,
// CSC folded into Wq, defer-max (T13), v_max3 (T17), m97 gload_lds GEMM staging.

#define B_ 4
#define N_ 2048
#define D_ 768
#define H_ 12
#define DH_ 64
#define CSC_ 0.18033688011112042f  // SCALE * log2(e)

typedef __attribute__((ext_vector_type(8))) short bf8_t;   // 8 bf16 (MFMA A/B frag)
typedef __attribute__((ext_vector_type(4))) float f4_t;    // 16x16 C/D frag
typedef __attribute__((ext_vector_type(16))) float f16v;   // 32x32 C/D frag
typedef __attribute__((ext_vector_type(4))) int i4_t;

__device__ __forceinline__ short f2b(float f) {            // fp32 -> bf16 RNE
  union { float f; unsigned u; } v; v.f = f;
  unsigned r = v.u + 0x7FFFu + ((v.u >> 16) & 1u);
  return (short)(r >> 16);
}
__device__ __forceinline__ float b2f(short s) {
  union { unsigned u; float f; } v; v.u = ((unsigned)(unsigned short)s) << 16;
  return v.f;
}
__device__ __forceinline__ unsigned cvtpk(float lo, float hi) {
  unsigned r;
  asm("v_cvt_pk_bf16_f32 %0, %1, %2" : "=v"(r) : "v"(lo), "v"(hi));
  return r;
}
__device__ __forceinline__ void plswap(unsigned& a, unsigned& b) {
  asm("v_permlane32_swap_b32 %0, %1" : "+v"(a), "+v"(b));
}
__device__ __forceinline__ float max3f(float a, float b, float c) {
  float r;
  asm("v_max3_f32 %0, %1, %2, %3" : "=v"(r) : "v"(a), "v"(b), "v"(c));
  return r;
}

#define GLOAD_LDS16(gp, lp)                                                       \
  __builtin_amdgcn_global_load_lds(                                               \
      (const __attribute__((address_space(1))) void*)(gp),                        \
      (__attribute__((address_space(3))) void*)(lp), 16, 0, 0)

// ---------------- prep: x fp32 -> bf16 ----------------
__global__ __launch_bounds__(256) void k_convx(const float* __restrict__ x,
                                               short* __restrict__ xb) {
  int i = blockIdx.x * 256 + threadIdx.x;
  int base = i * 8;
  float4 a = *(const float4*)(x + base);
  float4 b = *(const float4*)(x + base + 4);
  bf8_t v;
  v[0] = f2b(a.x); v[1] = f2b(a.y); v[2] = f2b(a.z); v[3] = f2b(a.w);
  v[4] = f2b(b.x); v[5] = f2b(b.y); v[6] = f2b(b.z); v[7] = f2b(b.w);
  *(bf8_t*)(xb + base) = v;
}

// ------- prep: transpose weights fp32->bf16 into B^T layout; Wq pre-scaled -------
__global__ __launch_bounds__(256) void k_wtrans(const float* __restrict__ Wq,
                                                const float* __restrict__ Wk,
                                                const float* __restrict__ Wv,
                                                const float* __restrict__ Wo,
                                                short* __restrict__ WqkvT,
                                                short* __restrict__ WoT) {
  int z = blockIdx.z;
  const float* W = (z == 0) ? Wq : (z == 1) ? Wk : (z == 2) ? Wv : Wo;
  short* dst = (z < 3) ? (WqkvT + (size_t)z * D_ * D_) : WoT;
  float sc = (z == 0) ? CSC_ : 1.f;  // fold softmax scale*log2e into Wq
  __shared__ float T[64][65];
  int r0 = blockIdx.y * 64, c0 = blockIdx.x * 64;
  int tr = threadIdx.x >> 6, tc = threadIdx.x & 63;
#pragma unroll
  for (int i = 0; i < 16; ++i) {
    int r = tr + i * 4;
    T[r][tc] = W[(size_t)(r0 + r) * D_ + c0 + tc];
  }
  __syncthreads();
#pragma unroll
  for (int i = 0; i < 16; ++i) {
    int r = tr + i * 4;
    dst[(size_t)(c0 + r) * D_ + r0 + tc] = f2b(T[tc][r] * sc);
  }
}

// ------- GEMM (m97 staging): C[M x Ncol] = A[M x K] * BT[Ncol x K]^T -------
// 128x128 tile, BK=64, 4 waves, global_load_lds width-16 into linear LDS.
template <int MODE>
__global__ __launch_bounds__(256) void k_gemm(const short* __restrict__ A,
                                              const short* __restrict__ BT, int K,
                                              short* __restrict__ Qb, short* __restrict__ Kb,
                                              short* __restrict__ Vb,
                                              float* __restrict__ Cout, int ldc) {
  __shared__ short As[128 * 64];
  __shared__ short Bs[128 * 64];
  int row0 = blockIdx.y * 128, col0 = blockIdx.x * 128;
  int tid = threadIdx.x, lane = tid & 63, w = tid >> 6;
  int wr = w >> 1, wc = w & 1;
  int lr = lane & 15, lhi = lane >> 4;
  int srow = 32 * w + (lane >> 3);       // staging row base (per i: +8i)
  int sc8 = (lane & 7) * 8;              // staging col (shorts)
  char* asb = (char*)As + w * 4096;      // wave-uniform LDS dest bases
  char* bsb = (char*)Bs + w * 4096;
  f4_t acc[4][4];
#pragma unroll
  for (int mi = 0; mi < 4; ++mi)
#pragma unroll
    for (int ni = 0; ni < 4; ++ni) acc[mi][ni] = (f4_t){0.f, 0.f, 0.f, 0.f};

  for (int k0 = 0; k0 < K; k0 += 64) {
    __syncthreads();
#pragma unroll
    for (int i = 0; i < 4; ++i) {
      GLOAD_LDS16(A + (size_t)(row0 + srow + 8 * i) * K + k0 + sc8, asb + i * 1024);
      GLOAD_LDS16(BT + (size_t)(col0 + srow + 8 * i) * K + k0 + sc8, bsb + i * 1024);
    }
    __syncthreads();
#pragma unroll
    for (int kc = 0; kc < 2; ++kc) {
      bf8_t av[4], bv[4];
#pragma unroll
      for (int mi = 0; mi < 4; ++mi)
        av[mi] = *(const bf8_t*)(As + (64 * wr + 16 * mi + lr) * 64 + kc * 32 + lhi * 8);
#pragma unroll
      for (int ni = 0; ni < 4; ++ni)
        bv[ni] = *(const bf8_t*)(Bs + (64 * wc + 16 * ni + lr) * 64 + kc * 32 + lhi * 8);
#pragma unroll
      for (int mi = 0; mi < 4; ++mi)
#pragma unroll
        for (int ni = 0; ni < 4; ++ni)
          acc[mi][ni] = __builtin_amdgcn_mfma_f32_16x16x32_bf16(av[mi], bv[ni], acc[mi][ni], 0, 0, 0);
    }
  }
#pragma unroll
  for (int mi = 0; mi < 4; ++mi)
#pragma unroll
    for (int ni = 0; ni < 4; ++ni)
#pragma unroll
      for (int r = 0; r < 4; ++r) {
        int row = row0 + 64 * wr + 16 * mi + 4 * lhi + r;
        int col = col0 + 64 * wc + 16 * ni + lr;
        float v = acc[mi][ni][r];
        if (MODE == 0) {
          int which = col / 768;
          int cc2 = col - which * 768;
          int h = cc2 >> 6, dh = cc2 & 63;
          int b = row >> 11, n = row & 2047;
          size_t dst = (((size_t)(b * H_ + h)) * N_ + n) * DH_ + dh;
          short bv2 = f2b(v);
          if (which == 0) Qb[dst] = bv2;
          else if (which == 1) Kb[dst] = bv2;
          else Vb[dst] = bv2;
        } else {
          Cout[(size_t)row * ldc + col] = v;
        }
      }
}

// ---------------- V[bh][n][dh] -> Vt[bh][dh][n] ----------------
__global__ __launch_bounds__(256) void k_vtrans(const short* __restrict__ V,
                                                short* __restrict__ Vt) {
  int bh = blockIdx.y;
  int n0 = blockIdx.x * 64;
  __shared__ short T[64][72];
  int tr = threadIdx.x >> 6, tc = threadIdx.x & 63;
  const short* Vp = V + (size_t)bh * N_ * DH_;
  short* Vtp = Vt + (size_t)bh * DH_ * N_;
#pragma unroll
  for (int i = 0; i < 16; ++i) {
    int r = tr + i * 4;
    T[r][tc] = Vp[(size_t)(n0 + r) * DH_ + tc];
  }
  __syncthreads();
#pragma unroll
  for (int i = 0; i < 16; ++i) {
    int r = tr + i * 4;
    Vtp[(size_t)r * N_ + n0 + tc] = T[tc][r];
  }
}

// ---------------- Vmean[bh][dh] = (1/N) sum_n V[bh][n][dh] (reads Vt) ----------------
__global__ __launch_bounds__(256) void k_vmean(const short* __restrict__ Vt,
                                               float* __restrict__ Vmean) {
  int bh = blockIdx.x;
  int t = threadIdx.x;
  int dh = t >> 2, seg = t & 3;
  const short* rp = Vt + (size_t)bh * DH_ * N_ + (size_t)dh * N_ + seg * 512;
  float a0 = 0, a1 = 0, a2 = 0, a3 = 0, a4 = 0, a5 = 0, a6 = 0, a7 = 0;
#pragma unroll 4
  for (int j = 0; j < 64; ++j) {
    bf8_t v = *(const bf8_t*)(rp + j * 8);
    a0 += b2f(v[0]); a1 += b2f(v[1]); a2 += b2f(v[2]); a3 += b2f(v[3]);
    a4 += b2f(v[4]); a5 += b2f(v[5]); a6 += b2f(v[6]); a7 += b2f(v[7]);
  }
  float s = ((a0 + a1) + (a2 + a3)) + ((a4 + a5) + (a6 + a7));
  __shared__ float red[64][4];
  red[dh][seg] = s;
  __syncthreads();
  if (t < 64) {
    float* r4 = red[t];
    Vmean[bh * 64 + t] = (r4[0] + r4[1] + r4[2] + r4[3]) * (1.f / 2048.f);
  }
}

// -------- flash attention, swapped-QK^T 32x32; k-mask via MFMA bias column --------
__global__ __launch_bounds__(256, 3) void k_attn(const short* __restrict__ Q,
                                                 const short* __restrict__ Kg,
                                                 const short* __restrict__ Vtg,
                                                 const int* __restrict__ xmask,
                                                 const float* __restrict__ Vmean,
                                                 short* __restrict__ Aout) {
  int bh = blockIdx.y;
  int b = bh / H_, h = bh - b * H_;
  const short* Qp = Q + (size_t)bh * N_ * DH_;
  const short* Kp = Kg + (size_t)bh * N_ * DH_;
  const short* Vp = Vtg + (size_t)bh * DH_ * N_;
  const int* mk = xmask + b * N_;
  int q0 = blockIdx.x * 128;
  int tid = threadIdx.x, lane = tid & 63, w = tid >> 6;
  int lq = lane & 31, hi = lane >> 5;

  __shared__ char smem[32768];  // 2 x (K 8KB + V 8KB); epilogue reuses after barrier

  bf8_t qf[4];  // Q frags: B-operand of mfma(K,Q); Wq pre-scaled by CSC
#pragma unroll
  for (int kc = 0; kc < 4; ++kc)
    qf[kc] = *(const bf8_t*)(Qp + (size_t)(q0 + 32 * w + lq) * DH_ + 16 * kc + 8 * hi);

  int qm = mk[q0 + 32 * w + lq];                       // q-mask (epilogue only)
  short NEGBIG = f2b(-1e30f);
  bf8_t qbf = {hi ? (short)0 : (short)0x3F80, 0, 0, 0, 0, 0, 0, 0};  // bias B-frag (1.0)

  f16v acco[2];
#pragma unroll
  for (int i = 0; i < 16; ++i) { acco[0][i] = 0.f; acco[1][i] = 0.f; }
  float m = -1e29f, lsum = 0.f;  // m floor: keeps masked p = exp2(-1e30 - m) == 0

  auto STAGE = [&](int key0, int buf) {
    char* kb_ = smem + buf * 16384;
    char* vb_ = kb_ + 8192;
    int row = tid >> 3;
    int cb = (tid & 7) * 16;
    char* lk = kb_ + ((tid >> 6) << 10);
    char* lv = vb_ + ((tid >> 6) << 10);
#pragma unroll
    for (int rr = 0; rr < 2; ++rr) {
      int r2 = row + rr * 32;
      int sw = cb ^ ((r2 & 7) << 4);
      GLOAD_LDS16((const char*)(Kp + (size_t)(key0 + r2) * DH_) + sw, lk + rr * 4096);
      GLOAD_LDS16((const char*)(Vp + (size_t)r2 * N_ + key0) + sw, lv + rr * 4096);
    }
  };

  STAGE(0, 0);
  __syncthreads();

  for (int kt = 0; kt < N_ / 64; ++kt) {
    int cur = kt & 1;
    if (kt + 1 < N_ / 64) STAGE((kt + 1) * 64, cur ^ 1);

    const char* kbase = smem + cur * 16384;
    const char* vbase = kbase + 8192;
    int key0 = kt * 64;

    // ---- QK^T (S^T[key][q]) + k-mask bias via extra MFMA ----
    f16v accs[2];
#pragma unroll
    for (int i = 0; i < 16; ++i) { accs[0][i] = 0.f; accs[1][i] = 0.f; }
    int swz = (lq & 7) << 4;
#pragma unroll
    for (int kc = 0; kc < 4; ++kc) {
      int colb = (32 * kc + 16 * hi) ^ swz;
      bf8_t k0 = *(const bf8_t*)(kbase + lq * 128 + colb);
      bf8_t k1 = *(const bf8_t*)(kbase + (32 + lq) * 128 + colb);
      accs[0] = __builtin_amdgcn_mfma_f32_32x32x16_bf16(k0, qf[kc], accs[0], 0, 0, 0);
      accs[1] = __builtin_amdgcn_mfma_f32_32x32x16_bf16(k1, qf[kc], accs[1], 0, 0, 0);
    }
    {
      int mk0 = mk[key0 + lq];
      int mk1 = mk[key0 + 32 + lq];
      bf8_t bf0 = {(hi || mk0) ? (short)0 : NEGBIG, 0, 0, 0, 0, 0, 0, 0};
      bf8_t bf1 = {(hi || mk1) ? (short)0 : NEGBIG, 0, 0, 0, 0, 0, 0, 0};
      accs[0] = __builtin_amdgcn_mfma_f32_32x32x16_bf16(bf0, qbf, accs[0], 0, 0, 0);
      accs[1] = __builtin_amdgcn_mfma_f32_32x32x16_bf16(bf1, qbf, accs[1], 0, 0, 0);
    }

    // ---- per-lane online softmax (q = lq), defer-max THR=8 ----
    float mx = max3f(accs[0][0], accs[0][1], accs[0][2]);
#pragma unroll
    for (int i = 3; i < 15; i += 2) mx = max3f(mx, accs[0][i], accs[0][i + 1]);
    mx = max3f(mx, accs[0][15], accs[1][0]);
#pragma unroll
    for (int i = 1; i < 15; i += 2) mx = max3f(mx, accs[1][i], accs[1][i + 1]);
    mx = fmaxf(mx, accs[1][15]);
    mx = fmaxf(mx, __shfl_xor(mx, 32));
    if (!__all(mx <= m + 8.f)) {
      float mnew = fmaxf(m, mx);
      float sc = __builtin_amdgcn_exp2f(m - mnew);
      m = mnew;
      lsum *= sc;
#pragma unroll
      for (int i = 0; i < 16; ++i) { acco[0][i] *= sc; acco[1][i] *= sc; }
    }
    float psa[4] = {0.f, 0.f, 0.f, 0.f};
#pragma unroll
    for (int kb2 = 0; kb2 < 2; ++kb2)
#pragma unroll
      for (int r = 0; r < 16; ++r) {
        float p = __builtin_amdgcn_exp2f(accs[kb2][r] - m);
        accs[kb2][r] = p;
        psa[r & 3] += p;
      }
    float ps = (psa[0] + psa[1]) + (psa[2] + psa[3]);
    ps += __shfl_xor(ps, 32);
    lsum += ps;

    // ---- PV: O^T += V^T * P^T; P frags via cvt_pk + permlane32_swap ----
#pragma unroll
    for (int kc = 0; kc < 4; ++kc) {
      int kb2 = kc >> 1, rb = (kc & 1) * 8;
      unsigned a_ = cvtpk(accs[kb2][rb + 0], accs[kb2][rb + 1]);
      unsigned b_ = cvtpk(accs[kb2][rb + 4], accs[kb2][rb + 5]);
      unsigned c_ = cvtpk(accs[kb2][rb + 2], accs[kb2][rb + 3]);
      unsigned d_ = cvtpk(accs[kb2][rb + 6], accs[kb2][rb + 7]);
      plswap(a_, b_);
      plswap(c_, d_);
      union { i4_t i; bf8_t v; } pu;
      pu.i = (i4_t){(int)a_, (int)c_, (int)b_, (int)d_};
      int colb = (32 * kc + 16 * hi) ^ swz;
      bf8_t v0 = *(const bf8_t*)(vbase + lq * 128 + colb);
      bf8_t v1 = *(const bf8_t*)(vbase + (32 + lq) * 128 + colb);
      acco[0] = __builtin_amdgcn_mfma_f32_32x32x16_bf16(v0, pu.v, acco[0], 0, 0, 0);
      acco[1] = __builtin_amdgcn_mfma_f32_32x32x16_bf16(v1, pu.v, acco[1], 0, 0, 0);
    }

    __syncthreads();
  }
  __syncthreads();  // all waves done with K/V buffers before Os reuse (race fix)

  // ---- epilogue: masked-q rows -> Vmean; O^T -> LDS transpose -> coalesced store ----
  float inv = 1.f / lsum;
  float vm[2][16];
#pragma unroll
  for (int dhb = 0; dhb < 2; ++dhb)
#pragma unroll
    for (int rq = 0; rq < 4; ++rq) {
      float4 tv = *(const float4*)(Vmean + bh * 64 + 32 * dhb + 8 * rq + 4 * hi);
      vm[dhb][4 * rq + 0] = tv.x; vm[dhb][4 * rq + 1] = tv.y;
      vm[dhb][4 * rq + 2] = tv.z; vm[dhb][4 * rq + 3] = tv.w;
    }
  unsigned* Os = (unsigned*)smem + w * 1152;
#pragma unroll
  for (int dhb = 0; dhb < 2; ++dhb)
#pragma unroll
    for (int r = 0; r < 16; r += 2) {
      float v0 = qm ? acco[dhb][r] * inv : vm[dhb][r];
      float v1 = qm ? acco[dhb][r + 1] * inv : vm[dhb][r + 1];
      unsigned pk = cvtpk(v0, v1);
      int colu = 16 * dhb + ((r & 3) >> 1) + 4 * (r >> 2) + 2 * hi;
      Os[lq * 36 + colu] = pk;
    }
#pragma unroll
  for (int it = 0; it < 4; ++it) {
    int q = (lane >> 3) + 8 * it;
    i4_t vv = *(const i4_t*)(Os + q * 36 + 4 * (lane & 7));
    union { i4_t i; bf8_t s; } u2;
    u2.i = vv;
    size_t off = ((size_t)b * N_ + q0 + 32 * w + q) * D_ + h * DH_ + 8 * (lane & 7);
    *(bf8_t*)(Aout + off) = u2.s;
  }
}

extern "C" void kernel_launch(void* const* d_in, const int* in_sizes, int n_in,
                              void* d_out, int out_size, void* d_ws, size_t ws_size,
                              hipStream_t stream) {
  (void)in_sizes; (void)n_in; (void)out_size; (void)ws_size;
  const float* x  = (const float*)d_in[0];
  const int*   xm = (const int*)d_in[1];
  const float* Wq = (const float*)d_in[2];
  const float* Wk = (const float*)d_in[3];
  const float* Wv = (const float*)d_in[4];
  const float* Wo = (const float*)d_in[5];
  float* out = (float*)d_out;
  char* ws = (char*)d_ws;

  short* x_bf  = (short*)(ws + 0);
  short* WqkvT = (short*)(ws + 12582912);
  short* WoT   = (short*)(ws + 16121856);
  short* Qb    = (short*)(ws + 17301504);
  short* Kb    = (short*)(ws + 29884416);
  short* Vb    = (short*)(ws + 42467328);
  short* Vt    = (short*)(ws + 55050240);
  short* Ao    = (short*)(ws + 67633152);
  float* Vmean = (float*)(ws + 0);  // reuses x_bf region (dead after k_gemm<0>)

  k_convx<<<3072, 256, 0, stream>>>(x, x_bf);
  k_wtrans<<<dim3(12, 12, 4), 256, 0, stream>>>(Wq, Wk, Wv, Wo, WqkvT, WoT);
  k_gemm<0><<<dim3(18, 64), 256, 0, stream>>>(x_bf, WqkvT, 768, Qb, Kb, Vb, nullptr, 0);
  k_vtrans<<<dim3(32, 48), 256, 0, stream>>>(Vb, Vt);
  k_vmean<<<48, 256, 0, stream>>>(Vt, Vmean);
  k_attn<<<dim3(16, 48), 256, 0, stream>>>(Qb, Kb, Vt, xm, Vmean, Ao);
  k_gemm<1><<<dim3(6, 64), 256, 0, stream>>>(Ao, WoT, 768, nullptr, nullptr, nullptr, out, 768);
}

// Round 4
// 142.680 us; speedup vs baseline: 1.2605x; 1.2605x over previous
//
#include <hip/hip_runtime.h>

// Attention_73375221285454: fused MHA block on MI355X (gfx950)
// B=4 N=2048 D=768 H=12 DH=64. fp32 in/out, bf16 MFMA internally.
// Round 4: mask compaction (4x less attn work): per-batch valid-index lists,
// gathered/compacted K,V (zero-padded to 64), per-lane Q gather, tail-only
// bias MFMA, Vmean fill kernel for masked-q rows. GEMM staging reverted to
// round-2 padded-LDS (r3's gload_lds linear regressed ~17us at K=768).

#define B_ 4
#define N_ 2048
#define D_ 768
#define H_ 12
#define DH_ 64
#define CSC_ 0.18033688011112042f  // SCALE * log2(e)

typedef __attribute__((ext_vector_type(8))) short bf8_t;   // 8 bf16 (MFMA A/B frag)
typedef __attribute__((ext_vector_type(4))) float f4_t;    // 16x16 C/D frag
typedef __attribute__((ext_vector_type(16))) float f16v;   // 32x32 C/D frag
typedef __attribute__((ext_vector_type(4))) int i4_t;

__device__ __forceinline__ short f2b(float f) {            // fp32 -> bf16 RNE
  union { float f; unsigned u; } v; v.f = f;
  unsigned r = v.u + 0x7FFFu + ((v.u >> 16) & 1u);
  return (short)(r >> 16);
}
__device__ __forceinline__ float b2f(short s) {
  union { unsigned u; float f; } v; v.u = ((unsigned)(unsigned short)s) << 16;
  return v.f;
}
__device__ __forceinline__ unsigned cvtpk(float lo, float hi) {
  unsigned r;
  asm("v_cvt_pk_bf16_f32 %0, %1, %2" : "=v"(r) : "v"(lo), "v"(hi));
  return r;
}
__device__ __forceinline__ void plswap(unsigned& a, unsigned& b) {
  asm("v_permlane32_swap_b32 %0, %1" : "+v"(a), "+v"(b));
}
__device__ __forceinline__ float max3f(float a, float b, float c) {
  float r;
  asm("v_max3_f32 %0, %1, %2, %3" : "=v"(r) : "v"(a), "v"(b), "v"(c));
  return r;
}

#define GLOAD_LDS16(gp, lp)                                                       \
  __builtin_amdgcn_global_load_lds(                                               \
      (const __attribute__((address_space(1))) void*)(gp),                        \
      (__attribute__((address_space(3))) void*)(lp), 16, 0, 0)

// ---------------- prep: x fp32 -> bf16 ----------------
__global__ __launch_bounds__(256) void k_convx(const float* __restrict__ x,
                                               short* __restrict__ xb) {
  int i = blockIdx.x * 256 + threadIdx.x;
  int base = i * 8;
  float4 a = *(const float4*)(x + base);
  float4 b = *(const float4*)(x + base + 4);
  bf8_t v;
  v[0] = f2b(a.x); v[1] = f2b(a.y); v[2] = f2b(a.z); v[3] = f2b(a.w);
  v[4] = f2b(b.x); v[5] = f2b(b.y); v[6] = f2b(b.z); v[7] = f2b(b.w);
  *(bf8_t*)(xb + base) = v;
}

// ------- prep: transpose weights fp32->bf16 into B^T layout; Wq pre-scaled -------
__global__ __launch_bounds__(256) void k_wtrans(const float* __restrict__ Wq,
                                                const float* __restrict__ Wk,
                                                const float* __restrict__ Wv,
                                                const float* __restrict__ Wo,
                                                short* __restrict__ WqkvT,
                                                short* __restrict__ WoT) {
  int z = blockIdx.z;
  const float* W = (z == 0) ? Wq : (z == 1) ? Wk : (z == 2) ? Wv : Wo;
  short* dst = (z < 3) ? (WqkvT + (size_t)z * D_ * D_) : WoT;
  float sc = (z == 0) ? CSC_ : 1.f;
  __shared__ float T[64][65];
  int r0 = blockIdx.y * 64, c0 = blockIdx.x * 64;
  int tr = threadIdx.x >> 6, tc = threadIdx.x & 63;
#pragma unroll
  for (int i = 0; i < 16; ++i) {
    int r = tr + i * 4;
    T[r][tc] = W[(size_t)(r0 + r) * D_ + c0 + tc];
  }
  __syncthreads();
#pragma unroll
  for (int i = 0; i < 16; ++i) {
    int r = tr + i * 4;
    dst[(size_t)(c0 + r) * D_ + r0 + tc] = f2b(T[tc][r] * sc);
  }
}

// ------- GEMM (round-2 staging): C[M x Ncol] = A[M x K] * BT[Ncol x K]^T -------
template <int MODE>
__global__ __launch_bounds__(256) void k_gemm(const short* __restrict__ A,
                                              const short* __restrict__ BT, int K,
                                              short* __restrict__ Qb, short* __restrict__ Kb,
                                              short* __restrict__ Vb,
                                              float* __restrict__ Cout, int ldc) {
  __shared__ short As[128 * 72];  // +8 pad: 2-way bank alias (free, m136)
  __shared__ short Bs[128 * 72];
  int row0 = blockIdx.y * 128, col0 = blockIdx.x * 128;
  int tid = threadIdx.x, lane = tid & 63, w = tid >> 6;
  int wr = w >> 1, wc = w & 1;
  int lr = lane & 15, lhi = lane >> 4;
  f4_t acc[4][4];
#pragma unroll
  for (int mi = 0; mi < 4; ++mi)
#pragma unroll
    for (int ni = 0; ni < 4; ++ni) acc[mi][ni] = (f4_t){0.f, 0.f, 0.f, 0.f};

  for (int k0 = 0; k0 < K; k0 += 64) {
    __syncthreads();
#pragma unroll
    for (int cc = 0; cc < 4; ++cc) {
      int c = tid + cc * 256;
      int r = c >> 3, c8 = (c & 7) * 8;
      *(bf8_t*)(As + r * 72 + c8) = *(const bf8_t*)(A + (size_t)(row0 + r) * K + k0 + c8);
    }
#pragma unroll
    for (int cc = 0; cc < 4; ++cc) {
      int c = tid + cc * 256;
      int r = c >> 3, c8 = (c & 7) * 8;
      *(bf8_t*)(Bs + r * 72 + c8) = *(const bf8_t*)(BT + (size_t)(col0 + r) * K + k0 + c8);
    }
    __syncthreads();
#pragma unroll
    for (int kc = 0; kc < 2; ++kc) {
      bf8_t av[4], bv[4];
#pragma unroll
      for (int mi = 0; mi < 4; ++mi)
        av[mi] = *(const bf8_t*)(As + (64 * wr + 16 * mi + lr) * 72 + kc * 32 + lhi * 8);
#pragma unroll
      for (int ni = 0; ni < 4; ++ni)
        bv[ni] = *(const bf8_t*)(Bs + (64 * wc + 16 * ni + lr) * 72 + kc * 32 + lhi * 8);
#pragma unroll
      for (int mi = 0; mi < 4; ++mi)
#pragma unroll
        for (int ni = 0; ni < 4; ++ni)
          acc[mi][ni] = __builtin_amdgcn_mfma_f32_16x16x32_bf16(av[mi], bv[ni], acc[mi][ni], 0, 0, 0);
    }
  }
#pragma unroll
  for (int mi = 0; mi < 4; ++mi)
#pragma unroll
    for (int ni = 0; ni < 4; ++ni)
#pragma unroll
      for (int r = 0; r < 4; ++r) {
        int row = row0 + 64 * wr + 16 * mi + 4 * lhi + r;
        int col = col0 + 64 * wc + 16 * ni + lr;
        float v = acc[mi][ni][r];
        if (MODE == 0) {
          int which = col / 768;
          int cc2 = col - which * 768;
          int h = cc2 >> 6, dh = cc2 & 63;
          int b = row >> 11, n = row & 2047;
          size_t dst = (((size_t)(b * H_ + h)) * N_ + n) * DH_ + dh;
          short bv2 = f2b(v);
          if (which == 0) Qb[dst] = bv2;
          else if (which == 1) Kb[dst] = bv2;
          else Vb[dst] = bv2;
        } else {
          Cout[(size_t)row * ldc + col] = v;
        }
      }
}

// ---------------- per-batch valid-index list (order-preserving scan) ----------------
__global__ __launch_bounds__(256) void k_maskidx(const int* __restrict__ xmask,
                                                 int* __restrict__ idx,
                                                 int* __restrict__ cnt) {
  int b = blockIdx.x, t = threadIdx.x;
  const int* mp = xmask + b * N_;
  int loc[8], c = 0;
#pragma unroll
  for (int j = 0; j < 8; ++j) {
    int n = t * 8 + j;
    if (mp[n]) loc[c++] = n;
  }
  __shared__ int sc[256];
  sc[t] = c;
  __syncthreads();
  for (int off = 1; off < 256; off <<= 1) {
    int v = (t >= off) ? sc[t - off] : 0;
    __syncthreads();
    sc[t] += v;
    __syncthreads();
  }
  int base = sc[t] - c;
  int* op = idx + b * N_;
  for (int j = 0; j < c; ++j) op[base + j] = loc[j];
  if (t == 255) cnt[b] = sc[255];
}

// ---------------- Vmean stage A: per-(bh,chunk) partial sums (deterministic) ----------------
__global__ __launch_bounds__(256) void k_vmeanA(const short* __restrict__ Vb,
                                                float* __restrict__ part) {
  int bh = blockIdx.y, ch = blockIdx.x, t = threadIdx.x;
  int rg = t >> 3, cg = t & 7;
  const short* vp = Vb + ((size_t)bh * N_ + ch * 256 + rg) * DH_ + cg * 8;
  float a[8] = {0, 0, 0, 0, 0, 0, 0, 0};
#pragma unroll
  for (int k = 0; k < 8; ++k) {
    bf8_t v = *(const bf8_t*)(vp + (size_t)32 * k * DH_);
#pragma unroll
    for (int e = 0; e < 8; ++e) a[e] += b2f(v[e]);
  }
  __shared__ float red[8][32][8];
#pragma unroll
  for (int e = 0; e < 8; ++e) red[cg][rg][e] = a[e];
  __syncthreads();
  if (t < 64) {
    int g = t >> 3, j = t & 7;
    float s = 0;
#pragma unroll
    for (int i = 0; i < 32; ++i) s += red[g][i][j];
    part[((size_t)bh * 8 + ch) * 64 + g * 8 + j] = s;
  }
}

// ---------------- Vmean stage B: reduce 8 partials ----------------
__global__ __launch_bounds__(256) void k_vmeanB(const float* __restrict__ part,
                                                float* __restrict__ Vmean) {
  int i = blockIdx.x * 256 + threadIdx.x;
  if (i >= 48 * 64) return;
  int bh = i >> 6, dh = i & 63;
  float s = 0;
#pragma unroll
  for (int c = 0; c < 8; ++c) s += part[((size_t)bh * 8 + c) * 64 + dh];
  Vmean[i] = s * (1.f / 2048.f);
}

// -------- gather K,V by idx into compacted Kc[bh][j][dh], Vtc[bh][dh][j] --------
// zero-pads rows/cols in [cnt, cnt_padded64).
__global__ __launch_bounds__(256) void k_gather(const short* __restrict__ Kb,
                                                const short* __restrict__ Vb,
                                                const int* __restrict__ idx,
                                                const int* __restrict__ cnt,
                                                short* __restrict__ Kc,
                                                short* __restrict__ Vtc) {
  int bh = blockIdx.y, b = bh / H_;
  int j0 = blockIdx.x * 64;
  int cn = cnt[b];
  int cp = (cn + 63) & ~63;
  if (j0 >= cp) return;
  int t = threadIdx.x;
  __shared__ int sidx[64];
  __shared__ short vt[64][72];
  if (t < 64) sidx[t] = (j0 + t < cn) ? idx[b * N_ + j0 + t] : -1;
  __syncthreads();
  int r = t >> 2, c16 = (t & 3) * 16;
  int src = sidx[r];
  const bf8_t zz = {0, 0, 0, 0, 0, 0, 0, 0};
#pragma unroll
  for (int u = 0; u < 2; ++u) {
    bf8_t kv = (src >= 0) ? *(const bf8_t*)(Kb + ((size_t)bh * N_ + src) * DH_ + c16 + u * 8) : zz;
    bf8_t vv = (src >= 0) ? *(const bf8_t*)(Vb + ((size_t)bh * N_ + src) * DH_ + c16 + u * 8) : zz;
    *(bf8_t*)(Kc + ((size_t)bh * N_ + j0 + r) * DH_ + c16 + u * 8) = kv;
    *(bf8_t*)(&vt[r][c16 + u * 8]) = vv;
  }
  __syncthreads();
  int dh = t >> 2;
#pragma unroll
  for (int u = 0; u < 2; ++u) {
    bf8_t ov;
#pragma unroll
    for (int e = 0; e < 8; ++e) ov[e] = vt[c16 + u * 8 + e][dh];
    *(bf8_t*)(Vtc + ((size_t)bh * DH_ + dh) * N_ + j0 + c16 + u * 8) = ov;
  }
}

// -------- fill masked-q rows of Ao with Vmean (uniform-softmax result) --------
__global__ __launch_bounds__(256) void k_fill(const int* __restrict__ xmask,
                                              const float* __restrict__ Vmean,
                                              short* __restrict__ Ao) {
  int b = blockIdx.y;
  int n = blockIdx.x * 32 + (threadIdx.x >> 3);
  int cg = threadIdx.x & 7;
  if (xmask[b * N_ + n]) return;
#pragma unroll
  for (int k = 0; k < 12; ++k) {
    int col = cg * 8 + k * 64;
    int h = col >> 6, dh = col & 63;
    const float* vp = Vmean + ((size_t)b * H_ + h) * 64 + dh;
    bf8_t ov;
#pragma unroll
    for (int e = 0; e < 8; ++e) ov[e] = f2b(vp[e]);
    *(bf8_t*)(Ao + ((size_t)b * N_ + n) * D_ + col) = ov;
  }
}

// -------- flash attention on COMPACTED q/k (swapped-QK^T 32x32) --------
__global__ __launch_bounds__(256, 3) void k_attn(const short* __restrict__ Q,
                                                 const short* __restrict__ Kcg,
                                                 const short* __restrict__ Vtcg,
                                                 const int* __restrict__ idx,
                                                 const int* __restrict__ cnt,
                                                 short* __restrict__ Aout) {
  int bh = blockIdx.y;
  int b = bh / H_, h = bh - b * H_;
  int cn = cnt[b];
  int nqt = (cn + 127) >> 7;
  if ((int)blockIdx.x >= nqt) return;  // block-uniform: whole block exits, no barrier
  int nkt = (cn + 63) >> 6;
  const short* Qp = Q + (size_t)bh * N_ * DH_;
  const short* Kp = Kcg + (size_t)bh * N_ * DH_;
  const short* Vp = Vtcg + (size_t)bh * DH_ * N_;
  const int* ip = idx + b * N_;
  int q0 = blockIdx.x * 128;
  int tid = threadIdx.x, lane = tid & 63, w = tid >> 6;
  int lq = lane & 31, hi = lane >> 5;

  __shared__ char smem[32768];

  int qrow = q0 + 32 * w + lq;
  int qn = ip[qrow < cn ? qrow : cn - 1];  // clamp tail (stores guarded later)

  bf8_t qf[4];  // gathered Q frags (per-lane global addresses)
#pragma unroll
  for (int kc = 0; kc < 4; ++kc)
    qf[kc] = *(const bf8_t*)(Qp + (size_t)qn * DH_ + 16 * kc + 8 * hi);

  short NEGBIG = f2b(-1e30f);
  bf8_t qbf = {hi ? (short)0 : (short)0x3F80, 0, 0, 0, 0, 0, 0, 0};  // bias B (1.0)

  f16v acco[2];
#pragma unroll
  for (int i = 0; i < 16; ++i) { acco[0][i] = 0.f; acco[1][i] = 0.f; }
  float m = -1e29f, lsum = 0.f;

  auto STAGE = [&](int key0, int buf) {
    char* kb_ = smem + buf * 16384;
    char* vb_ = kb_ + 8192;
    int row = tid >> 3;
    int cb = (tid & 7) * 16;
    char* lk = kb_ + ((tid >> 6) << 10);
    char* lv = vb_ + ((tid >> 6) << 10);
#pragma unroll
    for (int rr = 0; rr < 2; ++rr) {
      int r2 = row + rr * 32;
      int sw = cb ^ ((r2 & 7) << 4);
      GLOAD_LDS16((const char*)(Kp + (size_t)(key0 + r2) * DH_) + sw, lk + rr * 4096);
      GLOAD_LDS16((const char*)(Vp + (size_t)r2 * N_ + key0) + sw, lv + rr * 4096);
    }
  };

  STAGE(0, 0);
  __syncthreads();

  for (int kt = 0; kt < nkt; ++kt) {
    int cur = kt & 1;
    if (kt + 1 < nkt) STAGE((kt + 1) * 64, cur ^ 1);

    const char* kbase = smem + cur * 16384;
    const char* vbase = kbase + 8192;
    int key0 = kt * 64;

    // ---- QK^T (S^T[key][q]); all staged keys valid except final-tile tail ----
    f16v accs[2];
#pragma unroll
    for (int i = 0; i < 16; ++i) { accs[0][i] = 0.f; accs[1][i] = 0.f; }
    int swz = (lq & 7) << 4;
    __builtin_amdgcn_s_setprio(1);
#pragma unroll
    for (int kc = 0; kc < 4; ++kc) {
      int colb = (32 * kc + 16 * hi) ^ swz;
      bf8_t k0 = *(const bf8_t*)(kbase + lq * 128 + colb);
      bf8_t k1 = *(const bf8_t*)(kbase + (32 + lq) * 128 + colb);
      accs[0] = __builtin_amdgcn_mfma_f32_32x32x16_bf16(k0, qf[kc], accs[0], 0, 0, 0);
      accs[1] = __builtin_amdgcn_mfma_f32_32x32x16_bf16(k1, qf[kc], accs[1], 0, 0, 0);
    }
    __builtin_amdgcn_s_setprio(0);
    if (key0 + 64 > cn) {  // tail guard: keys j >= cn get -1e30 bias
      bf8_t bf0 = {(hi || key0 + lq < cn) ? (short)0 : NEGBIG, 0, 0, 0, 0, 0, 0, 0};
      bf8_t bf1 = {(hi || key0 + 32 + lq < cn) ? (short)0 : NEGBIG, 0, 0, 0, 0, 0, 0, 0};
      accs[0] = __builtin_amdgcn_mfma_f32_32x32x16_bf16(bf0, qbf, accs[0], 0, 0, 0);
      accs[1] = __builtin_amdgcn_mfma_f32_32x32x16_bf16(bf1, qbf, accs[1], 0, 0, 0);
    }

    // ---- per-lane online softmax (q = lq), defer-max THR=8 ----
    float mx = max3f(accs[0][0], accs[0][1], accs[0][2]);
#pragma unroll
    for (int i = 3; i < 15; i += 2) mx = max3f(mx, accs[0][i], accs[0][i + 1]);
    mx = max3f(mx, accs[0][15], accs[1][0]);
#pragma unroll
    for (int i = 1; i < 15; i += 2) mx = max3f(mx, accs[1][i], accs[1][i + 1]);
    mx = fmaxf(mx, accs[1][15]);
    mx = fmaxf(mx, __shfl_xor(mx, 32));
    if (!__all(mx <= m + 8.f)) {
      float mnew = fmaxf(m, mx);
      float sc = __builtin_amdgcn_exp2f(m - mnew);
      m = mnew;
      lsum *= sc;
#pragma unroll
      for (int i = 0; i < 16; ++i) { acco[0][i] *= sc; acco[1][i] *= sc; }
    }
    float psa[4] = {0.f, 0.f, 0.f, 0.f};
#pragma unroll
    for (int kb2 = 0; kb2 < 2; ++kb2)
#pragma unroll
      for (int r = 0; r < 16; ++r) {
        float p = __builtin_amdgcn_exp2f(accs[kb2][r] - m);
        accs[kb2][r] = p;
        psa[r & 3] += p;
      }
    float ps = (psa[0] + psa[1]) + (psa[2] + psa[3]);
    ps += __shfl_xor(ps, 32);
    lsum += ps;

    // ---- PV: O^T += V^T * P^T; P frags via cvt_pk + permlane32_swap ----
    __builtin_amdgcn_s_setprio(1);
#pragma unroll
    for (int kc = 0; kc < 4; ++kc) {
      int kb2 = kc >> 1, rb = (kc & 1) * 8;
      unsigned a_ = cvtpk(accs[kb2][rb + 0], accs[kb2][rb + 1]);
      unsigned b_ = cvtpk(accs[kb2][rb + 4], accs[kb2][rb + 5]);
      unsigned c_ = cvtpk(accs[kb2][rb + 2], accs[kb2][rb + 3]);
      unsigned d_ = cvtpk(accs[kb2][rb + 6], accs[kb2][rb + 7]);
      plswap(a_, b_);
      plswap(c_, d_);
      union { i4_t i; bf8_t v; } pu;
      pu.i = (i4_t){(int)a_, (int)c_, (int)b_, (int)d_};
      int colb = (32 * kc + 16 * hi) ^ swz;
      bf8_t v0 = *(const bf8_t*)(vbase + lq * 128 + colb);
      bf8_t v1 = *(const bf8_t*)(vbase + (32 + lq) * 128 + colb);
      acco[0] = __builtin_amdgcn_mfma_f32_32x32x16_bf16(v0, pu.v, acco[0], 0, 0, 0);
      acco[1] = __builtin_amdgcn_mfma_f32_32x32x16_bf16(v1, pu.v, acco[1], 0, 0, 0);
    }
    __builtin_amdgcn_s_setprio(0);

    __syncthreads();
  }
  __syncthreads();  // all waves done with K/V buffers before Os reuse

  // ---- epilogue: O^T -> LDS transpose -> guarded scatter store via idx ----
  float inv = 1.f / lsum;
  unsigned* Os = (unsigned*)smem + w * 1152;
#pragma unroll
  for (int dhb = 0; dhb < 2; ++dhb)
#pragma unroll
    for (int r = 0; r < 16; r += 2) {
      unsigned pk = cvtpk(acco[dhb][r] * inv, acco[dhb][r + 1] * inv);
      int colu = 16 * dhb + ((r & 3) >> 1) + 4 * (r >> 2) + 2 * hi;
      Os[lq * 36 + colu] = pk;
    }
#pragma unroll
  for (int it = 0; it < 4; ++it) {
    int q = (lane >> 3) + 8 * it;
    int qr2 = q0 + 32 * w + q;
    if (qr2 < cn) {
      int n = ip[qr2];
      i4_t vv = *(const i4_t*)(Os + q * 36 + 4 * (lane & 7));
      union { i4_t i; bf8_t s; } u2;
      u2.i = vv;
      size_t off = ((size_t)b * N_ + n) * D_ + h * DH_ + 8 * (lane & 7);
      *(bf8_t*)(Aout + off) = u2.s;
    }
  }
}

extern "C" void kernel_launch(void* const* d_in, const int* in_sizes, int n_in,
                              void* d_out, int out_size, void* d_ws, size_t ws_size,
                              hipStream_t stream) {
  (void)in_sizes; (void)n_in; (void)out_size; (void)ws_size;
  const float* x  = (const float*)d_in[0];
  const int*   xm = (const int*)d_in[1];
  const float* Wq = (const float*)d_in[2];
  const float* Wk = (const float*)d_in[3];
  const float* Wv = (const float*)d_in[4];
  const float* Wo = (const float*)d_in[5];
  float* out = (float*)d_out;
  char* ws = (char*)d_ws;

  // [0,12582912): x_bf during QKV-GEMM, then reused as Ao (attn output).
  short* x_bf  = (short*)(ws + 0);
  short* Ao    = (short*)(ws + 0);
  // [12582912,16121856): WqkvT during QKV-GEMM, then aux (idx/cnt/part/Vmean).
  short* WqkvT = (short*)(ws + 12582912);
  int*   idxb  = (int*)(ws + 12582912);    // 32768 B
  int*   cntb  = (int*)(ws + 12615680);    // 64 B
  float* part  = (float*)(ws + 12615744);  // 98304 B
  float* Vmean = (float*)(ws + 12714048);  // 12288 B (ends 12726336)
  short* WoT   = (short*)(ws + 16121856);
  short* Qb    = (short*)(ws + 17301504);
  short* Kb    = (short*)(ws + 29884416);
  short* Vb    = (short*)(ws + 42467328);
  short* Kc    = (short*)(ws + 55050240);
  short* Vtc   = (short*)(ws + 67633152);  // total 80,216,064 B

  k_convx<<<3072, 256, 0, stream>>>(x, x_bf);
  k_wtrans<<<dim3(12, 12, 4), 256, 0, stream>>>(Wq, Wk, Wv, Wo, WqkvT, WoT);
  k_gemm<0><<<dim3(18, 64), 256, 0, stream>>>(x_bf, WqkvT, 768, Qb, Kb, Vb, nullptr, 0);
  k_maskidx<<<4, 256, 0, stream>>>(xm, idxb, cntb);
  k_vmeanA<<<dim3(8, 48), 256, 0, stream>>>(Vb, part);
  k_vmeanB<<<12, 256, 0, stream>>>(part, Vmean);
  k_gather<<<dim3(32, 48), 256, 0, stream>>>(Kb, Vb, idxb, cntb, Kc, Vtc);
  k_attn<<<dim3(16, 48), 256, 0, stream>>>(Qb, Kc, Vtc, idxb, cntb, Ao);
  k_fill<<<dim3(64, 4), 256, 0, stream>>>(xm, Vmean, Ao);
  k_gemm<1><<<dim3(6, 64), 256, 0, stream>>>(Ao, WoT, 768, nullptr, nullptr, nullptr, out, 768);
}

// Round 5
// 135.968 us; speedup vs baseline: 1.3227x; 1.0494x over previous
//
#include <hip/hip_runtime.h>

// Attention_73375221285454: fused MHA block on MI355X (gfx950)
// B=4 N=2048 D=768 H=12 DH=64. fp32 in/out, bf16 MFMA internally.
// Round 5: k_gemm staging -> T14 async-STAGE split (issue global loads for
// tile t+1 BEFORE compute(t); barrier; ds_write; barrier). Single 36KB LDS
// buffer, 72-pitch (conflict-free reads). Rest identical to round 4
// (mask-compacted flash attention, Vmean fill, etc).

#define B_ 4
#define N_ 2048
#define D_ 768
#define H_ 12
#define DH_ 64
#define CSC_ 0.18033688011112042f  // SCALE * log2(e)

typedef __attribute__((ext_vector_type(8))) short bf8_t;   // 8 bf16 (MFMA A/B frag)
typedef __attribute__((ext_vector_type(4))) float f4_t;    // 16x16 C/D frag
typedef __attribute__((ext_vector_type(16))) float f16v;   // 32x32 C/D frag
typedef __attribute__((ext_vector_type(4))) int i4_t;

__device__ __forceinline__ short f2b(float f) {            // fp32 -> bf16 RNE
  union { float f; unsigned u; } v; v.f = f;
  unsigned r = v.u + 0x7FFFu + ((v.u >> 16) & 1u);
  return (short)(r >> 16);
}
__device__ __forceinline__ float b2f(short s) {
  union { unsigned u; float f; } v; v.u = ((unsigned)(unsigned short)s) << 16;
  return v.f;
}
__device__ __forceinline__ unsigned cvtpk(float lo, float hi) {
  unsigned r;
  asm("v_cvt_pk_bf16_f32 %0, %1, %2" : "=v"(r) : "v"(lo), "v"(hi));
  return r;
}
__device__ __forceinline__ void plswap(unsigned& a, unsigned& b) {
  asm("v_permlane32_swap_b32 %0, %1" : "+v"(a), "+v"(b));
}
__device__ __forceinline__ float max3f(float a, float b, float c) {
  float r;
  asm("v_max3_f32 %0, %1, %2, %3" : "=v"(r) : "v"(a), "v"(b), "v"(c));
  return r;
}

#define GLOAD_LDS16(gp, lp)                                                       \
  __builtin_amdgcn_global_load_lds(                                               \
      (const __attribute__((address_space(1))) void*)(gp),                        \
      (__attribute__((address_space(3))) void*)(lp), 16, 0, 0)

// ---------------- prep: x fp32 -> bf16 ----------------
__global__ __launch_bounds__(256) void k_convx(const float* __restrict__ x,
                                               short* __restrict__ xb) {
  int i = blockIdx.x * 256 + threadIdx.x;
  int base = i * 8;
  float4 a = *(const float4*)(x + base);
  float4 b = *(const float4*)(x + base + 4);
  bf8_t v;
  v[0] = f2b(a.x); v[1] = f2b(a.y); v[2] = f2b(a.z); v[3] = f2b(a.w);
  v[4] = f2b(b.x); v[5] = f2b(b.y); v[6] = f2b(b.z); v[7] = f2b(b.w);
  *(bf8_t*)(xb + base) = v;
}

// ------- prep: transpose weights fp32->bf16 into B^T layout; Wq pre-scaled -------
__global__ __launch_bounds__(256) void k_wtrans(const float* __restrict__ Wq,
                                                const float* __restrict__ Wk,
                                                const float* __restrict__ Wv,
                                                const float* __restrict__ Wo,
                                                short* __restrict__ WqkvT,
                                                short* __restrict__ WoT) {
  int z = blockIdx.z;
  const float* W = (z == 0) ? Wq : (z == 1) ? Wk : (z == 2) ? Wv : Wo;
  short* dst = (z < 3) ? (WqkvT + (size_t)z * D_ * D_) : WoT;
  float sc = (z == 0) ? CSC_ : 1.f;
  __shared__ float T[64][65];
  int r0 = blockIdx.y * 64, c0 = blockIdx.x * 64;
  int tr = threadIdx.x >> 6, tc = threadIdx.x & 63;
#pragma unroll
  for (int i = 0; i < 16; ++i) {
    int r = tr + i * 4;
    T[r][tc] = W[(size_t)(r0 + r) * D_ + c0 + tc];
  }
  __syncthreads();
#pragma unroll
  for (int i = 0; i < 16; ++i) {
    int r = tr + i * 4;
    dst[(size_t)(c0 + r) * D_ + r0 + tc] = f2b(T[tc][r] * sc);
  }
}

// ------- GEMM (T14 staging): C[M x Ncol] = A[M x K] * BT[Ncol x K]^T -------
// 128x128 tile, BK=64, 4 waves. Loads for tile t+1 issued before compute(t):
// global latency hides under the MFMA phase; LDS write is a short lgkm-only
// phase between two barriers.
template <int MODE>
__global__ __launch_bounds__(256) void k_gemm(const short* __restrict__ A,
                                              const short* __restrict__ BT, int K,
                                              short* __restrict__ Qb, short* __restrict__ Kb,
                                              short* __restrict__ Vb,
                                              float* __restrict__ Cout, int ldc) {
  __shared__ short As[128 * 72];  // +8 pad: 2-way bank alias (free, m136)
  __shared__ short Bs[128 * 72];
  int row0 = blockIdx.y * 128, col0 = blockIdx.x * 128;
  int tid = threadIdx.x, lane = tid & 63, w = tid >> 6;
  int wr = w >> 1, wc = w & 1;
  int lr = lane & 15, lhi = lane >> 4;
  f4_t acc[4][4];
#pragma unroll
  for (int mi = 0; mi < 4; ++mi)
#pragma unroll
    for (int ni = 0; ni < 4; ++ni) acc[mi][ni] = (f4_t){0.f, 0.f, 0.f, 0.f};

  bf8_t ra[4], rb[4];  // in-flight staging regs (tile t+1)

  // prologue: tile 0 -> regs -> LDS
#pragma unroll
  for (int cc = 0; cc < 4; ++cc) {
    int c = tid + cc * 256, r = c >> 3, c8 = (c & 7) * 8;
    ra[cc] = *(const bf8_t*)(A + (size_t)(row0 + r) * K + c8);
    rb[cc] = *(const bf8_t*)(BT + (size_t)(col0 + r) * K + c8);
  }
#pragma unroll
  for (int cc = 0; cc < 4; ++cc) {
    int c = tid + cc * 256, r = c >> 3, c8 = (c & 7) * 8;
    *(bf8_t*)(As + r * 72 + c8) = ra[cc];
    *(bf8_t*)(Bs + r * 72 + c8) = rb[cc];
  }
  __syncthreads();

  int nt = K / 64;
  for (int t = 0; t < nt; ++t) {
    if (t + 1 < nt) {  // issue-early: next tile global->regs, lands during MFMA
      int k0 = (t + 1) * 64;
#pragma unroll
      for (int cc = 0; cc < 4; ++cc) {
        int c = tid + cc * 256, r = c >> 3, c8 = (c & 7) * 8;
        ra[cc] = *(const bf8_t*)(A + (size_t)(row0 + r) * K + k0 + c8);
        rb[cc] = *(const bf8_t*)(BT + (size_t)(col0 + r) * K + k0 + c8);
      }
    }
#pragma unroll
    for (int kc = 0; kc < 2; ++kc) {
      bf8_t av[4], bv[4];
#pragma unroll
      for (int mi = 0; mi < 4; ++mi)
        av[mi] = *(const bf8_t*)(As + (64 * wr + 16 * mi + lr) * 72 + kc * 32 + lhi * 8);
#pragma unroll
      for (int ni = 0; ni < 4; ++ni)
        bv[ni] = *(const bf8_t*)(Bs + (64 * wc + 16 * ni + lr) * 72 + kc * 32 + lhi * 8);
#pragma unroll
      for (int mi = 0; mi < 4; ++mi)
#pragma unroll
        for (int ni = 0; ni < 4; ++ni)
          acc[mi][ni] = __builtin_amdgcn_mfma_f32_16x16x32_bf16(av[mi], bv[ni], acc[mi][ni], 0, 0, 0);
    }
    __syncthreads();  // all waves done reading tile t
    if (t + 1 < nt) {  // write-late: publish tile t+1 (vmcnt wait sits here)
#pragma unroll
      for (int cc = 0; cc < 4; ++cc) {
        int c = tid + cc * 256, r = c >> 3, c8 = (c & 7) * 8;
        *(bf8_t*)(As + r * 72 + c8) = ra[cc];
        *(bf8_t*)(Bs + r * 72 + c8) = rb[cc];
      }
      __syncthreads();
    }
  }
#pragma unroll
  for (int mi = 0; mi < 4; ++mi)
#pragma unroll
    for (int ni = 0; ni < 4; ++ni)
#pragma unroll
      for (int r = 0; r < 4; ++r) {
        int row = row0 + 64 * wr + 16 * mi + 4 * lhi + r;
        int col = col0 + 64 * wc + 16 * ni + lr;
        float v = acc[mi][ni][r];
        if (MODE == 0) {
          int which = col / 768;
          int cc2 = col - which * 768;
          int h = cc2 >> 6, dh = cc2 & 63;
          int b = row >> 11, n = row & 2047;
          size_t dst = (((size_t)(b * H_ + h)) * N_ + n) * DH_ + dh;
          short bv2 = f2b(v);
          if (which == 0) Qb[dst] = bv2;
          else if (which == 1) Kb[dst] = bv2;
          else Vb[dst] = bv2;
        } else {
          Cout[(size_t)row * ldc + col] = v;
        }
      }
}

// ---------------- per-batch valid-index list (order-preserving scan) ----------------
__global__ __launch_bounds__(256) void k_maskidx(const int* __restrict__ xmask,
                                                 int* __restrict__ idx,
                                                 int* __restrict__ cnt) {
  int b = blockIdx.x, t = threadIdx.x;
  const int* mp = xmask + b * N_;
  int loc[8], c = 0;
#pragma unroll
  for (int j = 0; j < 8; ++j) {
    int n = t * 8 + j;
    if (mp[n]) loc[c++] = n;
  }
  __shared__ int sc[256];
  sc[t] = c;
  __syncthreads();
  for (int off = 1; off < 256; off <<= 1) {
    int v = (t >= off) ? sc[t - off] : 0;
    __syncthreads();
    sc[t] += v;
    __syncthreads();
  }
  int base = sc[t] - c;
  int* op = idx + b * N_;
  for (int j = 0; j < c; ++j) op[base + j] = loc[j];
  if (t == 255) cnt[b] = sc[255];
}

// ---------------- Vmean stage A: per-(bh,chunk) partial sums (deterministic) ----------------
__global__ __launch_bounds__(256) void k_vmeanA(const short* __restrict__ Vb,
                                                float* __restrict__ part) {
  int bh = blockIdx.y, ch = blockIdx.x, t = threadIdx.x;
  int rg = t >> 3, cg = t & 7;
  const short* vp = Vb + ((size_t)bh * N_ + ch * 256 + rg) * DH_ + cg * 8;
  float a[8] = {0, 0, 0, 0, 0, 0, 0, 0};
#pragma unroll
  for (int k = 0; k < 8; ++k) {
    bf8_t v = *(const bf8_t*)(vp + (size_t)32 * k * DH_);
#pragma unroll
    for (int e = 0; e < 8; ++e) a[e] += b2f(v[e]);
  }
  __shared__ float red[8][32][8];
#pragma unroll
  for (int e = 0; e < 8; ++e) red[cg][rg][e] = a[e];
  __syncthreads();
  if (t < 64) {
    int g = t >> 3, j = t & 7;
    float s = 0;
#pragma unroll
    for (int i = 0; i < 32; ++i) s += red[g][i][j];
    part[((size_t)bh * 8 + ch) * 64 + g * 8 + j] = s;
  }
}

// ---------------- Vmean stage B: reduce 8 partials ----------------
__global__ __launch_bounds__(256) void k_vmeanB(const float* __restrict__ part,
                                                float* __restrict__ Vmean) {
  int i = blockIdx.x * 256 + threadIdx.x;
  if (i >= 48 * 64) return;
  int bh = i >> 6, dh = i & 63;
  float s = 0;
#pragma unroll
  for (int c = 0; c < 8; ++c) s += part[((size_t)bh * 8 + c) * 64 + dh];
  Vmean[i] = s * (1.f / 2048.f);
}

// -------- gather K,V by idx into compacted Kc[bh][j][dh], Vtc[bh][dh][j] --------
__global__ __launch_bounds__(256) void k_gather(const short* __restrict__ Kb,
                                                const short* __restrict__ Vb,
                                                const int* __restrict__ idx,
                                                const int* __restrict__ cnt,
                                                short* __restrict__ Kc,
                                                short* __restrict__ Vtc) {
  int bh = blockIdx.y, b = bh / H_;
  int j0 = blockIdx.x * 64;
  int cn = cnt[b];
  int cp = (cn + 63) & ~63;
  if (j0 >= cp) return;
  int t = threadIdx.x;
  __shared__ int sidx[64];
  __shared__ short vt[64][72];
  if (t < 64) sidx[t] = (j0 + t < cn) ? idx[b * N_ + j0 + t] : -1;
  __syncthreads();
  int r = t >> 2, c16 = (t & 3) * 16;
  int src = sidx[r];
  const bf8_t zz = {0, 0, 0, 0, 0, 0, 0, 0};
#pragma unroll
  for (int u = 0; u < 2; ++u) {
    bf8_t kv = (src >= 0) ? *(const bf8_t*)(Kb + ((size_t)bh * N_ + src) * DH_ + c16 + u * 8) : zz;
    bf8_t vv = (src >= 0) ? *(const bf8_t*)(Vb + ((size_t)bh * N_ + src) * DH_ + c16 + u * 8) : zz;
    *(bf8_t*)(Kc + ((size_t)bh * N_ + j0 + r) * DH_ + c16 + u * 8) = kv;
    *(bf8_t*)(&vt[r][c16 + u * 8]) = vv;
  }
  __syncthreads();
  int dh = t >> 2;
#pragma unroll
  for (int u = 0; u < 2; ++u) {
    bf8_t ov;
#pragma unroll
    for (int e = 0; e < 8; ++e) ov[e] = vt[c16 + u * 8 + e][dh];
    *(bf8_t*)(Vtc + ((size_t)bh * DH_ + dh) * N_ + j0 + c16 + u * 8) = ov;
  }
}

// -------- fill masked-q rows of Ao with Vmean (uniform-softmax result) --------
__global__ __launch_bounds__(256) void k_fill(const int* __restrict__ xmask,
                                              const float* __restrict__ Vmean,
                                              short* __restrict__ Ao) {
  int b = blockIdx.y;
  int n = blockIdx.x * 32 + (threadIdx.x >> 3);
  int cg = threadIdx.x & 7;
  if (xmask[b * N_ + n]) return;
#pragma unroll
  for (int k = 0; k < 12; ++k) {
    int col = cg * 8 + k * 64;
    int h = col >> 6, dh = col & 63;
    const float* vp = Vmean + ((size_t)b * H_ + h) * 64 + dh;
    bf8_t ov;
#pragma unroll
    for (int e = 0; e < 8; ++e) ov[e] = f2b(vp[e]);
    *(bf8_t*)(Ao + ((size_t)b * N_ + n) * D_ + col) = ov;
  }
}

// -------- flash attention on COMPACTED q/k (swapped-QK^T 32x32) --------
__global__ __launch_bounds__(256, 3) void k_attn(const short* __restrict__ Q,
                                                 const short* __restrict__ Kcg,
                                                 const short* __restrict__ Vtcg,
                                                 const int* __restrict__ idx,
                                                 const int* __restrict__ cnt,
                                                 short* __restrict__ Aout) {
  int bh = blockIdx.y;
  int b = bh / H_, h = bh - b * H_;
  int cn = cnt[b];
  int nqt = (cn + 127) >> 7;
  if ((int)blockIdx.x >= nqt) return;  // block-uniform exit
  int nkt = (cn + 63) >> 6;
  const short* Qp = Q + (size_t)bh * N_ * DH_;
  const short* Kp = Kcg + (size_t)bh * N_ * DH_;
  const short* Vp = Vtcg + (size_t)bh * DH_ * N_;
  const int* ip = idx + b * N_;
  int q0 = blockIdx.x * 128;
  int tid = threadIdx.x, lane = tid & 63, w = tid >> 6;
  int lq = lane & 31, hi = lane >> 5;

  __shared__ char smem[32768];

  int qrow = q0 + 32 * w + lq;
  int qn = ip[qrow < cn ? qrow : cn - 1];  // clamp tail (stores guarded later)

  bf8_t qf[4];
#pragma unroll
  for (int kc = 0; kc < 4; ++kc)
    qf[kc] = *(const bf8_t*)(Qp + (size_t)qn * DH_ + 16 * kc + 8 * hi);

  short NEGBIG = f2b(-1e30f);
  bf8_t qbf = {hi ? (short)0 : (short)0x3F80, 0, 0, 0, 0, 0, 0, 0};  // bias B (1.0)

  f16v acco[2];
#pragma unroll
  for (int i = 0; i < 16; ++i) { acco[0][i] = 0.f; acco[1][i] = 0.f; }
  float m = -1e29f, lsum = 0.f;

  auto STAGE = [&](int key0, int buf) {
    char* kb_ = smem + buf * 16384;
    char* vb_ = kb_ + 8192;
    int row = tid >> 3;
    int cb = (tid & 7) * 16;
    char* lk = kb_ + ((tid >> 6) << 10);
    char* lv = vb_ + ((tid >> 6) << 10);
#pragma unroll
    for (int rr = 0; rr < 2; ++rr) {
      int r2 = row + rr * 32;
      int sw = cb ^ ((r2 & 7) << 4);
      GLOAD_LDS16((const char*)(Kp + (size_t)(key0 + r2) * DH_) + sw, lk + rr * 4096);
      GLOAD_LDS16((const char*)(Vp + (size_t)r2 * N_ + key0) + sw, lv + rr * 4096);
    }
  };

  STAGE(0, 0);
  __syncthreads();

  for (int kt = 0; kt < nkt; ++kt) {
    int cur = kt & 1;
    if (kt + 1 < nkt) STAGE((kt + 1) * 64, cur ^ 1);

    const char* kbase = smem + cur * 16384;
    const char* vbase = kbase + 8192;
    int key0 = kt * 64;

    f16v accs[2];
#pragma unroll
    for (int i = 0; i < 16; ++i) { accs[0][i] = 0.f; accs[1][i] = 0.f; }
    int swz = (lq & 7) << 4;
    __builtin_amdgcn_s_setprio(1);
#pragma unroll
    for (int kc = 0; kc < 4; ++kc) {
      int colb = (32 * kc + 16 * hi) ^ swz;
      bf8_t k0 = *(const bf8_t*)(kbase + lq * 128 + colb);
      bf8_t k1 = *(const bf8_t*)(kbase + (32 + lq) * 128 + colb);
      accs[0] = __builtin_amdgcn_mfma_f32_32x32x16_bf16(k0, qf[kc], accs[0], 0, 0, 0);
      accs[1] = __builtin_amdgcn_mfma_f32_32x32x16_bf16(k1, qf[kc], accs[1], 0, 0, 0);
    }
    __builtin_amdgcn_s_setprio(0);
    if (key0 + 64 > cn) {  // tail guard: keys j >= cn get -1e30 bias
      bf8_t bf0 = {(hi || key0 + lq < cn) ? (short)0 : NEGBIG, 0, 0, 0, 0, 0, 0, 0};
      bf8_t bf1 = {(hi || key0 + 32 + lq < cn) ? (short)0 : NEGBIG, 0, 0, 0, 0, 0, 0, 0};
      accs[0] = __builtin_amdgcn_mfma_f32_32x32x16_bf16(bf0, qbf, accs[0], 0, 0, 0);
      accs[1] = __builtin_amdgcn_mfma_f32_32x32x16_bf16(bf1, qbf, accs[1], 0, 0, 0);
    }

    float mx = max3f(accs[0][0], accs[0][1], accs[0][2]);
#pragma unroll
    for (int i = 3; i < 15; i += 2) mx = max3f(mx, accs[0][i], accs[0][i + 1]);
    mx = max3f(mx, accs[0][15], accs[1][0]);
#pragma unroll
    for (int i = 1; i < 15; i += 2) mx = max3f(mx, accs[1][i], accs[1][i + 1]);
    mx = fmaxf(mx, accs[1][15]);
    mx = fmaxf(mx, __shfl_xor(mx, 32));
    if (!__all(mx <= m + 8.f)) {
      float mnew = fmaxf(m, mx);
      float sc = __builtin_amdgcn_exp2f(m - mnew);
      m = mnew;
      lsum *= sc;
#pragma unroll
      for (int i = 0; i < 16; ++i) { acco[0][i] *= sc; acco[1][i] *= sc; }
    }
    float psa[4] = {0.f, 0.f, 0.f, 0.f};
#pragma unroll
    for (int kb2 = 0; kb2 < 2; ++kb2)
#pragma unroll
      for (int r = 0; r < 16; ++r) {
        float p = __builtin_amdgcn_exp2f(accs[kb2][r] - m);
        accs[kb2][r] = p;
        psa[r & 3] += p;
      }
    float ps = (psa[0] + psa[1]) + (psa[2] + psa[3]);
    ps += __shfl_xor(ps, 32);
    lsum += ps;

    __builtin_amdgcn_s_setprio(1);
#pragma unroll
    for (int kc = 0; kc < 4; ++kc) {
      int kb2 = kc >> 1, rb = (kc & 1) * 8;
      unsigned a_ = cvtpk(accs[kb2][rb + 0], accs[kb2][rb + 1]);
      unsigned b_ = cvtpk(accs[kb2][rb + 4], accs[kb2][rb + 5]);
      unsigned c_ = cvtpk(accs[kb2][rb + 2], accs[kb2][rb + 3]);
      unsigned d_ = cvtpk(accs[kb2][rb + 6], accs[kb2][rb + 7]);
      plswap(a_, b_);
      plswap(c_, d_);
      union { i4_t i; bf8_t v; } pu;
      pu.i = (i4_t){(int)a_, (int)c_, (int)b_, (int)d_};
      int colb = (32 * kc + 16 * hi) ^ swz;
      bf8_t v0 = *(const bf8_t*)(vbase + lq * 128 + colb);
      bf8_t v1 = *(const bf8_t*)(vbase + (32 + lq) * 128 + colb);
      acco[0] = __builtin_amdgcn_mfma_f32_32x32x16_bf16(v0, pu.v, acco[0], 0, 0, 0);
      acco[1] = __builtin_amdgcn_mfma_f32_32x32x16_bf16(v1, pu.v, acco[1], 0, 0, 0);
    }
    __builtin_amdgcn_s_setprio(0);

    __syncthreads();
  }
  __syncthreads();  // all waves done with K/V buffers before Os reuse

  float inv = 1.f / lsum;
  unsigned* Os = (unsigned*)smem + w * 1152;
#pragma unroll
  for (int dhb = 0; dhb < 2; ++dhb)
#pragma unroll
    for (int r = 0; r < 16; r += 2) {
      unsigned pk = cvtpk(acco[dhb][r] * inv, acco[dhb][r + 1] * inv);
      int colu = 16 * dhb + ((r & 3) >> 1) + 4 * (r >> 2) + 2 * hi;
      Os[lq * 36 + colu] = pk;
    }
#pragma unroll
  for (int it = 0; it < 4; ++it) {
    int q = (lane >> 3) + 8 * it;
    int qr2 = q0 + 32 * w + q;
    if (qr2 < cn) {
      int n = ip[qr2];
      i4_t vv = *(const i4_t*)(Os + q * 36 + 4 * (lane & 7));
      union { i4_t i; bf8_t s; } u2;
      u2.i = vv;
      size_t off = ((size_t)b * N_ + n) * D_ + h * DH_ + 8 * (lane & 7);
      *(bf8_t*)(Aout + off) = u2.s;
    }
  }
}

extern "C" void kernel_launch(void* const* d_in, const int* in_sizes, int n_in,
                              void* d_out, int out_size, void* d_ws, size_t ws_size,
                              hipStream_t stream) {
  (void)in_sizes; (void)n_in; (void)out_size; (void)ws_size;
  const float* x  = (const float*)d_in[0];
  const int*   xm = (const int*)d_in[1];
  const float* Wq = (const float*)d_in[2];
  const float* Wk = (const float*)d_in[3];
  const float* Wv = (const float*)d_in[4];
  const float* Wo = (const float*)d_in[5];
  float* out = (float*)d_out;
  char* ws = (char*)d_ws;

  short* x_bf  = (short*)(ws + 0);
  short* Ao    = (short*)(ws + 0);         // reuses x_bf (dead after gemm<0>)
  short* WqkvT = (short*)(ws + 12582912);
  int*   idxb  = (int*)(ws + 12582912);    // aux overlays WqkvT after gemm<0>
  int*   cntb  = (int*)(ws + 12615680);
  float* part  = (float*)(ws + 12615744);
  float* Vmean = (float*)(ws + 12714048);
  short* WoT   = (short*)(ws + 16121856);
  short* Qb    = (short*)(ws + 17301504);
  short* Kb    = (short*)(ws + 29884416);
  short* Vb    = (short*)(ws + 42467328);
  short* Kc    = (short*)(ws + 55050240);
  short* Vtc   = (short*)(ws + 67633152);

  k_convx<<<3072, 256, 0, stream>>>(x, x_bf);
  k_wtrans<<<dim3(12, 12, 4), 256, 0, stream>>>(Wq, Wk, Wv, Wo, WqkvT, WoT);
  k_gemm<0><<<dim3(18, 64), 256, 0, stream>>>(x_bf, WqkvT, 768, Qb, Kb, Vb, nullptr, 0);
  k_maskidx<<<4, 256, 0, stream>>>(xm, idxb, cntb);
  k_vmeanA<<<dim3(8, 48), 256, 0, stream>>>(Vb, part);
  k_vmeanB<<<12, 256, 0, stream>>>(part, Vmean);
  k_gather<<<dim3(32, 48), 256, 0, stream>>>(Kb, Vb, idxb, cntb, Kc, Vtc);
  k_attn<<<dim3(16, 48), 256, 0, stream>>>(Qb, Kc, Vtc, idxb, cntb, Ao);
  k_fill<<<dim3(64, 4), 256, 0, stream>>>(xm, Vmean, Ao);
  k_gemm<1><<<dim3(6, 64), 256, 0, stream>>>(Ao, WoT, 768, nullptr, nullptr, nullptr, out, 768);
}

// Round 6
// 133.973 us; speedup vs baseline: 1.3424x; 1.0149x over previous
//
#include <hip/hip_runtime.h>

// Attention_73375221285454: fused MHA block on MI355X (gfx950)
// B=4 N=2048 D=768 H=12 DH=64. fp32 in/out, bf16 MFMA internally.
// Round 6: T1 bijective XCD swizzle on both GEMMs (A-panel reuse lands on one
// XCD -> L2 hits cover the vmcnt stall); x->bf16 conversion fused into
// k_gemm<0> A-staging (k_convx deleted; convert in write-late phase via
// v_cvt_pk_bf16_f32). Rest identical to round 5.

#define B_ 4
#define N_ 2048
#define D_ 768
#define H_ 12
#define DH_ 64
#define CSC_ 0.18033688011112042f  // SCALE * log2(e)

typedef __attribute__((ext_vector_type(8))) short bf8_t;   // 8 bf16 (MFMA A/B frag)
typedef __attribute__((ext_vector_type(4))) float f4_t;    // 16x16 C/D frag
typedef __attribute__((ext_vector_type(16))) float f16v;   // 32x32 C/D frag
typedef __attribute__((ext_vector_type(4))) int i4_t;

__device__ __forceinline__ short f2b(float f) {            // fp32 -> bf16 RNE
  union { float f; unsigned u; } v; v.f = f;
  unsigned r = v.u + 0x7FFFu + ((v.u >> 16) & 1u);
  return (short)(r >> 16);
}
__device__ __forceinline__ float b2f(short s) {
  union { unsigned u; float f; } v; v.u = ((unsigned)(unsigned short)s) << 16;
  return v.f;
}
__device__ __forceinline__ unsigned cvtpk(float lo, float hi) {
  unsigned r;
  asm("v_cvt_pk_bf16_f32 %0, %1, %2" : "=v"(r) : "v"(lo), "v"(hi));
  return r;
}
__device__ __forceinline__ void plswap(unsigned& a, unsigned& b) {
  asm("v_permlane32_swap_b32 %0, %1" : "+v"(a), "+v"(b));
}
__device__ __forceinline__ float max3f(float a, float b, float c) {
  float r;
  asm("v_max3_f32 %0, %1, %2, %3" : "=v"(r) : "v"(a), "v"(b), "v"(c));
  return r;
}

#define GLOAD_LDS16(gp, lp)                                                       \
  __builtin_amdgcn_global_load_lds(                                               \
      (const __attribute__((address_space(1))) void*)(gp),                        \
      (__attribute__((address_space(3))) void*)(lp), 16, 0, 0)

// ------- prep: transpose weights fp32->bf16 into B^T layout; Wq pre-scaled -------
__global__ __launch_bounds__(256) void k_wtrans(const float* __restrict__ Wq,
                                                const float* __restrict__ Wk,
                                                const float* __restrict__ Wv,
                                                const float* __restrict__ Wo,
                                                short* __restrict__ WqkvT,
                                                short* __restrict__ WoT) {
  int z = blockIdx.z;
  const float* W = (z == 0) ? Wq : (z == 1) ? Wk : (z == 2) ? Wv : Wo;
  short* dst = (z < 3) ? (WqkvT + (size_t)z * D_ * D_) : WoT;
  float sc = (z == 0) ? CSC_ : 1.f;
  __shared__ float T[64][65];
  int r0 = blockIdx.y * 64, c0 = blockIdx.x * 64;
  int tr = threadIdx.x >> 6, tc = threadIdx.x & 63;
#pragma unroll
  for (int i = 0; i < 16; ++i) {
    int r = tr + i * 4;
    T[r][tc] = W[(size_t)(r0 + r) * D_ + c0 + tc];
  }
  __syncthreads();
#pragma unroll
  for (int i = 0; i < 16; ++i) {
    int r = tr + i * 4;
    dst[(size_t)(c0 + r) * D_ + r0 + tc] = f2b(T[tc][r] * sc);
  }
}

// ------- GEMM (T14 staging + T1 XCD swizzle): C = A[M x K] * BT[Ncol x K]^T -------
// 128x128 tile, BK=64, 4 waves. AFP32: A is fp32 (x input), converted to bf16
// in the write-late phase (loads stay raw in flight -> latency hidden).
template <int MODE, int AFP32>
__global__ __launch_bounds__(256) void k_gemm(const void* __restrict__ Ain,
                                              const short* __restrict__ BT, int K,
                                              short* __restrict__ Qb, short* __restrict__ Kb,
                                              short* __restrict__ Vb,
                                              float* __restrict__ Cout, int ldc) {
  __shared__ short As[128 * 72];  // +8 pad: 2-way bank alias (free, m136)
  __shared__ short Bs[128 * 72];
  // T1: bijective XCD swizzle (nwg % 8 == 0 for both launches)
  int gx = gridDim.x;
  int nwg = gx * gridDim.y;
  int flat = blockIdx.y * gx + blockIdx.x;
  int cpx = nwg >> 3;
  int swzb = (flat & 7) * cpx + (flat >> 3);
  int row0 = (swzb / gx) * 128, col0 = (swzb % gx) * 128;

  int tid = threadIdx.x, lane = tid & 63, w = tid >> 6;
  int wr = w >> 1, wc = w & 1;
  int lr = lane & 15, lhi = lane >> 4;
  f4_t acc[4][4];
#pragma unroll
  for (int mi = 0; mi < 4; ++mi)
#pragma unroll
    for (int ni = 0; ni < 4; ++ni) acc[mi][ni] = (f4_t){0.f, 0.f, 0.f, 0.f};

  const float* Af = (const float*)Ain;   // AFP32 path
  const short* Ab = (const short*)Ain;   // bf16 path
  float4 raf0[4], raf1[4];               // fp32 A in flight (fully unrolled idx)
  bf8_t ra[4], rb[4];                    // bf16 in flight

  // prologue: tile 0 -> regs -> LDS
#pragma unroll
  for (int cc = 0; cc < 4; ++cc) {
    int c = tid + cc * 256, r = c >> 3, c8 = (c & 7) * 8;
    if (AFP32) {
      raf0[cc] = *(const float4*)(Af + (size_t)(row0 + r) * K + c8);
      raf1[cc] = *(const float4*)(Af + (size_t)(row0 + r) * K + c8 + 4);
    } else {
      ra[cc] = *(const bf8_t*)(Ab + (size_t)(row0 + r) * K + c8);
    }
    rb[cc] = *(const bf8_t*)(BT + (size_t)(col0 + r) * K + c8);
  }
#pragma unroll
  for (int cc = 0; cc < 4; ++cc) {
    int c = tid + cc * 256, r = c >> 3, c8 = (c & 7) * 8;
    if (AFP32) {
      union { i4_t i; bf8_t v; } u;
      u.i = (i4_t){(int)cvtpk(raf0[cc].x, raf0[cc].y), (int)cvtpk(raf0[cc].z, raf0[cc].w),
                   (int)cvtpk(raf1[cc].x, raf1[cc].y), (int)cvtpk(raf1[cc].z, raf1[cc].w)};
      *(bf8_t*)(As + r * 72 + c8) = u.v;
    } else {
      *(bf8_t*)(As + r * 72 + c8) = ra[cc];
    }
    *(bf8_t*)(Bs + r * 72 + c8) = rb[cc];
  }
  __syncthreads();

  int nt = K / 64;
  for (int t = 0; t < nt; ++t) {
    if (t + 1 < nt) {  // issue-early: next tile global->regs, lands during MFMA
      int k0 = (t + 1) * 64;
#pragma unroll
      for (int cc = 0; cc < 4; ++cc) {
        int c = tid + cc * 256, r = c >> 3, c8 = (c & 7) * 8;
        if (AFP32) {
          raf0[cc] = *(const float4*)(Af + (size_t)(row0 + r) * K + k0 + c8);
          raf1[cc] = *(const float4*)(Af + (size_t)(row0 + r) * K + k0 + c8 + 4);
        } else {
          ra[cc] = *(const bf8_t*)(Ab + (size_t)(row0 + r) * K + k0 + c8);
        }
        rb[cc] = *(const bf8_t*)(BT + (size_t)(col0 + r) * K + k0 + c8);
      }
    }
#pragma unroll
    for (int kc = 0; kc < 2; ++kc) {
      bf8_t av[4], bv[4];
#pragma unroll
      for (int mi = 0; mi < 4; ++mi)
        av[mi] = *(const bf8_t*)(As + (64 * wr + 16 * mi + lr) * 72 + kc * 32 + lhi * 8);
#pragma unroll
      for (int ni = 0; ni < 4; ++ni)
        bv[ni] = *(const bf8_t*)(Bs + (64 * wc + 16 * ni + lr) * 72 + kc * 32 + lhi * 8);
#pragma unroll
      for (int mi = 0; mi < 4; ++mi)
#pragma unroll
        for (int ni = 0; ni < 4; ++ni)
          acc[mi][ni] = __builtin_amdgcn_mfma_f32_16x16x32_bf16(av[mi], bv[ni], acc[mi][ni], 0, 0, 0);
    }
    __syncthreads();  // all waves done reading tile t
    if (t + 1 < nt) {  // write-late: publish tile t+1 (vmcnt wait sits here)
#pragma unroll
      for (int cc = 0; cc < 4; ++cc) {
        int c = tid + cc * 256, r = c >> 3, c8 = (c & 7) * 8;
        if (AFP32) {
          union { i4_t i; bf8_t v; } u;
          u.i = (i4_t){(int)cvtpk(raf0[cc].x, raf0[cc].y), (int)cvtpk(raf0[cc].z, raf0[cc].w),
                       (int)cvtpk(raf1[cc].x, raf1[cc].y), (int)cvtpk(raf1[cc].z, raf1[cc].w)};
          *(bf8_t*)(As + r * 72 + c8) = u.v;
        } else {
          *(bf8_t*)(As + r * 72 + c8) = ra[cc];
        }
        *(bf8_t*)(Bs + r * 72 + c8) = rb[cc];
      }
      __syncthreads();
    }
  }
#pragma unroll
  for (int mi = 0; mi < 4; ++mi)
#pragma unroll
    for (int ni = 0; ni < 4; ++ni)
#pragma unroll
      for (int r = 0; r < 4; ++r) {
        int row = row0 + 64 * wr + 16 * mi + 4 * lhi + r;
        int col = col0 + 64 * wc + 16 * ni + lr;
        float v = acc[mi][ni][r];
        if (MODE == 0) {
          int which = col / 768;
          int cc2 = col - which * 768;
          int h = cc2 >> 6, dh = cc2 & 63;
          int b = row >> 11, n = row & 2047;
          size_t dst = (((size_t)(b * H_ + h)) * N_ + n) * DH_ + dh;
          short bv2 = f2b(v);
          if (which == 0) Qb[dst] = bv2;
          else if (which == 1) Kb[dst] = bv2;
          else Vb[dst] = bv2;
        } else {
          Cout[(size_t)row * ldc + col] = v;
        }
      }
}

// ---------------- per-batch valid-index list (order-preserving scan) ----------------
__global__ __launch_bounds__(256) void k_maskidx(const int* __restrict__ xmask,
                                                 int* __restrict__ idx,
                                                 int* __restrict__ cnt) {
  int b = blockIdx.x, t = threadIdx.x;
  const int* mp = xmask + b * N_;
  int loc[8], c = 0;
#pragma unroll
  for (int j = 0; j < 8; ++j) {
    int n = t * 8 + j;
    if (mp[n]) loc[c++] = n;
  }
  __shared__ int sc[256];
  sc[t] = c;
  __syncthreads();
  for (int off = 1; off < 256; off <<= 1) {
    int v = (t >= off) ? sc[t - off] : 0;
    __syncthreads();
    sc[t] += v;
    __syncthreads();
  }
  int base = sc[t] - c;
  int* op = idx + b * N_;
  for (int j = 0; j < c; ++j) op[base + j] = loc[j];
  if (t == 255) cnt[b] = sc[255];
}

// ---------------- Vmean stage A: per-(bh,chunk) partial sums (deterministic) ----------------
__global__ __launch_bounds__(256) void k_vmeanA(const short* __restrict__ Vb,
                                                float* __restrict__ part) {
  int bh = blockIdx.y, ch = blockIdx.x, t = threadIdx.x;
  int rg = t >> 3, cg = t & 7;
  const short* vp = Vb + ((size_t)bh * N_ + ch * 256 + rg) * DH_ + cg * 8;
  float a[8] = {0, 0, 0, 0, 0, 0, 0, 0};
#pragma unroll
  for (int k = 0; k < 8; ++k) {
    bf8_t v = *(const bf8_t*)(vp + (size_t)32 * k * DH_);
#pragma unroll
    for (int e = 0; e < 8; ++e) a[e] += b2f(v[e]);
  }
  __shared__ float red[8][32][8];
#pragma unroll
  for (int e = 0; e < 8; ++e) red[cg][rg][e] = a[e];
  __syncthreads();
  if (t < 64) {
    int g = t >> 3, j = t & 7;
    float s = 0;
#pragma unroll
    for (int i = 0; i < 32; ++i) s += red[g][i][j];
    part[((size_t)bh * 8 + ch) * 64 + g * 8 + j] = s;
  }
}

// ---------------- Vmean stage B: reduce 8 partials ----------------
__global__ __launch_bounds__(256) void k_vmeanB(const float* __restrict__ part,
                                                float* __restrict__ Vmean) {
  int i = blockIdx.x * 256 + threadIdx.x;
  if (i >= 48 * 64) return;
  int bh = i >> 6, dh = i & 63;
  float s = 0;
#pragma unroll
  for (int c = 0; c < 8; ++c) s += part[((size_t)bh * 8 + c) * 64 + dh];
  Vmean[i] = s * (1.f / 2048.f);
}

// -------- gather K,V by idx into compacted Kc[bh][j][dh], Vtc[bh][dh][j] --------
__global__ __launch_bounds__(256) void k_gather(const short* __restrict__ Kb,
                                                const short* __restrict__ Vb,
                                                const int* __restrict__ idx,
                                                const int* __restrict__ cnt,
                                                short* __restrict__ Kc,
                                                short* __restrict__ Vtc) {
  int bh = blockIdx.y, b = bh / H_;
  int j0 = blockIdx.x * 64;
  int cn = cnt[b];
  int cp = (cn + 63) & ~63;
  if (j0 >= cp) return;
  int t = threadIdx.x;
  __shared__ int sidx[64];
  __shared__ short vt[64][72];
  if (t < 64) sidx[t] = (j0 + t < cn) ? idx[b * N_ + j0 + t] : -1;
  __syncthreads();
  int r = t >> 2, c16 = (t & 3) * 16;
  int src = sidx[r];
  const bf8_t zz = {0, 0, 0, 0, 0, 0, 0, 0};
#pragma unroll
  for (int u = 0; u < 2; ++u) {
    bf8_t kv = (src >= 0) ? *(const bf8_t*)(Kb + ((size_t)bh * N_ + src) * DH_ + c16 + u * 8) : zz;
    bf8_t vv = (src >= 0) ? *(const bf8_t*)(Vb + ((size_t)bh * N_ + src) * DH_ + c16 + u * 8) : zz;
    *(bf8_t*)(Kc + ((size_t)bh * N_ + j0 + r) * DH_ + c16 + u * 8) = kv;
    *(bf8_t*)(&vt[r][c16 + u * 8]) = vv;
  }
  __syncthreads();
  int dh = t >> 2;
#pragma unroll
  for (int u = 0; u < 2; ++u) {
    bf8_t ov;
#pragma unroll
    for (int e = 0; e < 8; ++e) ov[e] = vt[c16 + u * 8 + e][dh];
    *(bf8_t*)(Vtc + ((size_t)bh * DH_ + dh) * N_ + j0 + c16 + u * 8) = ov;
  }
}

// -------- fill masked-q rows of Ao with Vmean (uniform-softmax result) --------
__global__ __launch_bounds__(256) void k_fill(const int* __restrict__ xmask,
                                              const float* __restrict__ Vmean,
                                              short* __restrict__ Ao) {
  int b = blockIdx.y;
  int n = blockIdx.x * 32 + (threadIdx.x >> 3);
  int cg = threadIdx.x & 7;
  if (xmask[b * N_ + n]) return;
#pragma unroll
  for (int k = 0; k < 12; ++k) {
    int col = cg * 8 + k * 64;
    int h = col >> 6, dh = col & 63;
    const float* vp = Vmean + ((size_t)b * H_ + h) * 64 + dh;
    bf8_t ov;
#pragma unroll
    for (int e = 0; e < 8; ++e) ov[e] = f2b(vp[e]);
    *(bf8_t*)(Ao + ((size_t)b * N_ + n) * D_ + col) = ov;
  }
}

// -------- flash attention on COMPACTED q/k (swapped-QK^T 32x32) --------
__global__ __launch_bounds__(256, 3) void k_attn(const short* __restrict__ Q,
                                                 const short* __restrict__ Kcg,
                                                 const short* __restrict__ Vtcg,
                                                 const int* __restrict__ idx,
                                                 const int* __restrict__ cnt,
                                                 short* __restrict__ Aout) {
  int bh = blockIdx.y;
  int b = bh / H_, h = bh - b * H_;
  int cn = cnt[b];
  int nqt = (cn + 127) >> 7;
  if ((int)blockIdx.x >= nqt) return;  // block-uniform exit
  int nkt = (cn + 63) >> 6;
  const short* Qp = Q + (size_t)bh * N_ * DH_;
  const short* Kp = Kcg + (size_t)bh * N_ * DH_;
  const short* Vp = Vtcg + (size_t)bh * DH_ * N_;
  const int* ip = idx + b * N_;
  int q0 = blockIdx.x * 128;
  int tid = threadIdx.x, lane = tid & 63, w = tid >> 6;
  int lq = lane & 31, hi = lane >> 5;

  __shared__ char smem[32768];

  int qrow = q0 + 32 * w + lq;
  int qn = ip[qrow < cn ? qrow : cn - 1];  // clamp tail (stores guarded later)

  bf8_t qf[4];
#pragma unroll
  for (int kc = 0; kc < 4; ++kc)
    qf[kc] = *(const bf8_t*)(Qp + (size_t)qn * DH_ + 16 * kc + 8 * hi);

  short NEGBIG = f2b(-1e30f);
  bf8_t qbf = {hi ? (short)0 : (short)0x3F80, 0, 0, 0, 0, 0, 0, 0};  // bias B (1.0)

  f16v acco[2];
#pragma unroll
  for (int i = 0; i < 16; ++i) { acco[0][i] = 0.f; acco[1][i] = 0.f; }
  float m = -1e29f, lsum = 0.f;

  auto STAGE = [&](int key0, int buf) {
    char* kb_ = smem + buf * 16384;
    char* vb_ = kb_ + 8192;
    int row = tid >> 3;
    int cb = (tid & 7) * 16;
    char* lk = kb_ + ((tid >> 6) << 10);
    char* lv = vb_ + ((tid >> 6) << 10);
#pragma unroll
    for (int rr = 0; rr < 2; ++rr) {
      int r2 = row + rr * 32;
      int sw = cb ^ ((r2 & 7) << 4);
      GLOAD_LDS16((const char*)(Kp + (size_t)(key0 + r2) * DH_) + sw, lk + rr * 4096);
      GLOAD_LDS16((const char*)(Vp + (size_t)r2 * N_ + key0) + sw, lv + rr * 4096);
    }
  };

  STAGE(0, 0);
  __syncthreads();

  for (int kt = 0; kt < nkt; ++kt) {
    int cur = kt & 1;
    if (kt + 1 < nkt) STAGE((kt + 1) * 64, cur ^ 1);

    const char* kbase = smem + cur * 16384;
    const char* vbase = kbase + 8192;
    int key0 = kt * 64;

    f16v accs[2];
#pragma unroll
    for (int i = 0; i < 16; ++i) { accs[0][i] = 0.f; accs[1][i] = 0.f; }
    int swz = (lq & 7) << 4;
    __builtin_amdgcn_s_setprio(1);
#pragma unroll
    for (int kc = 0; kc < 4; ++kc) {
      int colb = (32 * kc + 16 * hi) ^ swz;
      bf8_t k0 = *(const bf8_t*)(kbase + lq * 128 + colb);
      bf8_t k1 = *(const bf8_t*)(kbase + (32 + lq) * 128 + colb);
      accs[0] = __builtin_amdgcn_mfma_f32_32x32x16_bf16(k0, qf[kc], accs[0], 0, 0, 0);
      accs[1] = __builtin_amdgcn_mfma_f32_32x32x16_bf16(k1, qf[kc], accs[1], 0, 0, 0);
    }
    __builtin_amdgcn_s_setprio(0);
    if (key0 + 64 > cn) {  // tail guard: keys j >= cn get -1e30 bias
      bf8_t bf0 = {(hi || key0 + lq < cn) ? (short)0 : NEGBIG, 0, 0, 0, 0, 0, 0, 0};
      bf8_t bf1 = {(hi || key0 + 32 + lq < cn) ? (short)0 : NEGBIG, 0, 0, 0, 0, 0, 0, 0};
      accs[0] = __builtin_amdgcn_mfma_f32_32x32x16_bf16(bf0, qbf, accs[0], 0, 0, 0);
      accs[1] = __builtin_amdgcn_mfma_f32_32x32x16_bf16(bf1, qbf, accs[1], 0, 0, 0);
    }

    float mx = max3f(accs[0][0], accs[0][1], accs[0][2]);
#pragma unroll
    for (int i = 3; i < 15; i += 2) mx = max3f(mx, accs[0][i], accs[0][i + 1]);
    mx = max3f(mx, accs[0][15], accs[1][0]);
#pragma unroll
    for (int i = 1; i < 15; i += 2) mx = max3f(mx, accs[1][i], accs[1][i + 1]);
    mx = fmaxf(mx, accs[1][15]);
    mx = fmaxf(mx, __shfl_xor(mx, 32));
    if (!__all(mx <= m + 8.f)) {
      float mnew = fmaxf(m, mx);
      float sc = __builtin_amdgcn_exp2f(m - mnew);
      m = mnew;
      lsum *= sc;
#pragma unroll
      for (int i = 0; i < 16; ++i) { acco[0][i] *= sc; acco[1][i] *= sc; }
    }
    float psa[4] = {0.f, 0.f, 0.f, 0.f};
#pragma unroll
    for (int kb2 = 0; kb2 < 2; ++kb2)
#pragma unroll
      for (int r = 0; r < 16; ++r) {
        float p = __builtin_amdgcn_exp2f(accs[kb2][r] - m);
        accs[kb2][r] = p;
        psa[r & 3] += p;
      }
    float ps = (psa[0] + psa[1]) + (psa[2] + psa[3]);
    ps += __shfl_xor(ps, 32);
    lsum += ps;

    __builtin_amdgcn_s_setprio(1);
#pragma unroll
    for (int kc = 0; kc < 4; ++kc) {
      int kb2 = kc >> 1, rb = (kc & 1) * 8;
      unsigned a_ = cvtpk(accs[kb2][rb + 0], accs[kb2][rb + 1]);
      unsigned b_ = cvtpk(accs[kb2][rb + 4], accs[kb2][rb + 5]);
      unsigned c_ = cvtpk(accs[kb2][rb + 2], accs[kb2][rb + 3]);
      unsigned d_ = cvtpk(accs[kb2][rb + 6], accs[kb2][rb + 7]);
      plswap(a_, b_);
      plswap(c_, d_);
      union { i4_t i; bf8_t v; } pu;
      pu.i = (i4_t){(int)a_, (int)c_, (int)b_, (int)d_};
      int colb = (32 * kc + 16 * hi) ^ swz;
      bf8_t v0 = *(const bf8_t*)(vbase + lq * 128 + colb);
      bf8_t v1 = *(const bf8_t*)(vbase + (32 + lq) * 128 + colb);
      acco[0] = __builtin_amdgcn_mfma_f32_32x32x16_bf16(v0, pu.v, acco[0], 0, 0, 0);
      acco[1] = __builtin_amdgcn_mfma_f32_32x32x16_bf16(v1, pu.v, acco[1], 0, 0, 0);
    }
    __builtin_amdgcn_s_setprio(0);

    __syncthreads();
  }
  __syncthreads();  // all waves done with K/V buffers before Os reuse

  float inv = 1.f / lsum;
  unsigned* Os = (unsigned*)smem + w * 1152;
#pragma unroll
  for (int dhb = 0; dhb < 2; ++dhb)
#pragma unroll
    for (int r = 0; r < 16; r += 2) {
      unsigned pk = cvtpk(acco[dhb][r] * inv, acco[dhb][r + 1] * inv);
      int colu = 16 * dhb + ((r & 3) >> 1) + 4 * (r >> 2) + 2 * hi;
      Os[lq * 36 + colu] = pk;
    }
#pragma unroll
  for (int it = 0; it < 4; ++it) {
    int q = (lane >> 3) + 8 * it;
    int qr2 = q0 + 32 * w + q;
    if (qr2 < cn) {
      int n = ip[qr2];
      i4_t vv = *(const i4_t*)(Os + q * 36 + 4 * (lane & 7));
      union { i4_t i; bf8_t s; } u2;
      u2.i = vv;
      size_t off = ((size_t)b * N_ + n) * D_ + h * DH_ + 8 * (lane & 7);
      *(bf8_t*)(Aout + off) = u2.s;
    }
  }
}

extern "C" void kernel_launch(void* const* d_in, const int* in_sizes, int n_in,
                              void* d_out, int out_size, void* d_ws, size_t ws_size,
                              hipStream_t stream) {
  (void)in_sizes; (void)n_in; (void)out_size; (void)ws_size;
  const float* x  = (const float*)d_in[0];
  const int*   xm = (const int*)d_in[1];
  const float* Wq = (const float*)d_in[2];
  const float* Wk = (const float*)d_in[3];
  const float* Wv = (const float*)d_in[4];
  const float* Wo = (const float*)d_in[5];
  float* out = (float*)d_out;
  char* ws = (char*)d_ws;

  short* Ao    = (short*)(ws + 0);         // attn output (12.6 MB)
  short* WqkvT = (short*)(ws + 12582912);
  int*   idxb  = (int*)(ws + 12582912);    // aux overlays WqkvT after gemm<0>... (safe: maskidx runs after gemm<0>)
  int*   cntb  = (int*)(ws + 12615680);
  float* part  = (float*)(ws + 12615744);
  float* Vmean = (float*)(ws + 12714048);
  short* WoT   = (short*)(ws + 16121856);
  short* Qb    = (short*)(ws + 17301504);
  short* Kb    = (short*)(ws + 29884416);
  short* Vb    = (short*)(ws + 42467328);
  short* Kc    = (short*)(ws + 55050240);
  short* Vtc   = (short*)(ws + 67633152);

  k_wtrans<<<dim3(12, 12, 4), 256, 0, stream>>>(Wq, Wk, Wv, Wo, WqkvT, WoT);
  k_gemm<0, 1><<<dim3(18, 64), 256, 0, stream>>>(x, WqkvT, 768, Qb, Kb, Vb, nullptr, 0);
  k_maskidx<<<4, 256, 0, stream>>>(xm, idxb, cntb);
  k_vmeanA<<<dim3(8, 48), 256, 0, stream>>>(Vb, part);
  k_vmeanB<<<12, 256, 0, stream>>>(part, Vmean);
  k_gather<<<dim3(32, 48), 256, 0, stream>>>(Kb, Vb, idxb, cntb, Kc, Vtc);
  k_attn<<<dim3(16, 48), 256, 0, stream>>>(Qb, Kc, Vtc, idxb, cntb, Ao);
  k_fill<<<dim3(64, 4), 256, 0, stream>>>(xm, Vmean, Ao);
  k_gemm<1, 0><<<dim3(6, 64), 256, 0, stream>>>(Ao, WoT, 768, nullptr, nullptr, nullptr, out, 768);
}

// Round 7
// 132.141 us; speedup vs baseline: 1.3610x; 1.0139x over previous
//
#include <hip/hip_runtime.h>

// Attention_73375221285454: fused MHA block on MI355X (gfx950)
// B=4 N=2048 D=768 H=12 DH=64. fp32 in/out, bf16 MFMA internally.
// Round 7: k_gemm rebuilt on the attn-kernel pipeline: double-buffered LDS,
// global_load_lds staging of tile t+1 issued before compute(t), ONE barrier
// per K-step, XOR-swizzle (pre-swizzled global source + swizzled ds_read,
// rule #21). bf16 A restored (k_convx back; r6 fp32-A fusion regressed).
// XCD swizzle kept (FETCH 70->54MB evidence). Attn path unchanged.

#define B_ 4
#define N_ 2048
#define D_ 768
#define H_ 12
#define DH_ 64
#define CSC_ 0.18033688011112042f  // SCALE * log2(e)

typedef __attribute__((ext_vector_type(8))) short bf8_t;   // 8 bf16 (MFMA A/B frag)
typedef __attribute__((ext_vector_type(4))) float f4_t;    // 16x16 C/D frag
typedef __attribute__((ext_vector_type(16))) float f16v;   // 32x32 C/D frag
typedef __attribute__((ext_vector_type(4))) int i4_t;

__device__ __forceinline__ short f2b(float f) {            // fp32 -> bf16 RNE
  union { float f; unsigned u; } v; v.f = f;
  unsigned r = v.u + 0x7FFFu + ((v.u >> 16) & 1u);
  return (short)(r >> 16);
}
__device__ __forceinline__ float b2f(short s) {
  union { unsigned u; float f; } v; v.u = ((unsigned)(unsigned short)s) << 16;
  return v.f;
}
__device__ __forceinline__ unsigned cvtpk(float lo, float hi) {
  unsigned r;
  asm("v_cvt_pk_bf16_f32 %0, %1, %2" : "=v"(r) : "v"(lo), "v"(hi));
  return r;
}
__device__ __forceinline__ void plswap(unsigned& a, unsigned& b) {
  asm("v_permlane32_swap_b32 %0, %1" : "+v"(a), "+v"(b));
}
__device__ __forceinline__ float max3f(float a, float b, float c) {
  float r;
  asm("v_max3_f32 %0, %1, %2, %3" : "=v"(r) : "v"(a), "v"(b), "v"(c));
  return r;
}

#define GLOAD_LDS16(gp, lp)                                                       \
  __builtin_amdgcn_global_load_lds(                                               \
      (const __attribute__((address_space(1))) void*)(gp),                        \
      (__attribute__((address_space(3))) void*)(lp), 16, 0, 0)

// ---------------- prep: x fp32 -> bf16 (BW-bound floor ~6us) ----------------
__global__ __launch_bounds__(256) void k_convx(const float* __restrict__ x,
                                               short* __restrict__ xb) {
  int i = blockIdx.x * 256 + threadIdx.x;
  int base = i * 8;
  float4 a = *(const float4*)(x + base);
  float4 b = *(const float4*)(x + base + 4);
  bf8_t v;
  v[0] = f2b(a.x); v[1] = f2b(a.y); v[2] = f2b(a.z); v[3] = f2b(a.w);
  v[4] = f2b(b.x); v[5] = f2b(b.y); v[6] = f2b(b.z); v[7] = f2b(b.w);
  *(bf8_t*)(xb + base) = v;
}

// ------- prep: transpose weights fp32->bf16 into B^T layout; Wq pre-scaled -------
__global__ __launch_bounds__(256) void k_wtrans(const float* __restrict__ Wq,
                                                const float* __restrict__ Wk,
                                                const float* __restrict__ Wv,
                                                const float* __restrict__ Wo,
                                                short* __restrict__ WqkvT,
                                                short* __restrict__ WoT) {
  int z = blockIdx.z;
  const float* W = (z == 0) ? Wq : (z == 1) ? Wk : (z == 2) ? Wv : Wo;
  short* dst = (z < 3) ? (WqkvT + (size_t)z * D_ * D_) : WoT;
  float sc = (z == 0) ? CSC_ : 1.f;
  __shared__ float T[64][65];
  int r0 = blockIdx.y * 64, c0 = blockIdx.x * 64;
  int tr = threadIdx.x >> 6, tc = threadIdx.x & 63;
#pragma unroll
  for (int i = 0; i < 16; ++i) {
    int r = tr + i * 4;
    T[r][tc] = W[(size_t)(r0 + r) * D_ + c0 + tc];
  }
  __syncthreads();
#pragma unroll
  for (int i = 0; i < 16; ++i) {
    int r = tr + i * 4;
    dst[(size_t)(c0 + r) * D_ + r0 + tc] = f2b(T[tc][r] * sc);
  }
}

// ------- GEMM (attn-style pipeline): C = A[M x K] * BT[Ncol x K]^T -------
// 128x128 tile, BK=64, 4 waves. Double-buffered LDS; global_load_lds for
// tile t+1 issued before compute(t); one barrier per K-step (its vmcnt
// drain is covered by the compute phase). XOR-swizzled layout (rule #21):
// linear LDS dest + pre-swizzled global src + swizzled ds_read.
template <int MODE>
__global__ __launch_bounds__(256) void k_gemm(const short* __restrict__ A,
                                              const short* __restrict__ BT, int K,
                                              short* __restrict__ Qb, short* __restrict__ Kb,
                                              short* __restrict__ Vb,
                                              float* __restrict__ Cout, int ldc) {
  __shared__ short As[2][128 * 64];  // 2 x 16KB
  __shared__ short Bs[2][128 * 64];  // 2 x 16KB  (total 64KB -> 2 blocks/CU)
  // T1: bijective XCD swizzle (nwg % 8 == 0 for both launches)
  int gx = gridDim.x;
  int nwg = gx * gridDim.y;
  int flat = blockIdx.y * gx + blockIdx.x;
  int cpx = nwg >> 3;
  int swzb = (flat & 7) * cpx + (flat >> 3);
  int row0 = (swzb / gx) * 128, col0 = (swzb % gx) * 128;

  int tid = threadIdx.x, lane = tid & 63, w = tid >> 6;
  int wr = w >> 1, wc = w & 1;
  int lr = lane & 15, lhi = lane >> 4;
  f4_t acc[4][4];
#pragma unroll
  for (int mi = 0; mi < 4; ++mi)
#pragma unroll
    for (int ni = 0; ni < 4; ++ni) acc[mi][ni] = (f4_t){0.f, 0.f, 0.f, 0.f};

  // staging geometry: wave w stages rows 32w..32w+31 (4 gloads x 8 rows),
  // lane l -> row sub = l>>3, byte col cb = (l&7)*16, src pre-swizzled by sub.
  int sub = lane >> 3;
  int scb = ((lane & 7) * 16) ^ (sub << 4);  // pre-swizzled global byte col
  auto STAGE = [&](int k0, int buf) {
    char* ab = (char*)As[buf] + (w << 12);
    char* bb = (char*)Bs[buf] + (w << 12);
#pragma unroll
    for (int i = 0; i < 4; ++i) {
      int r = 32 * w + 8 * i + sub;
      GLOAD_LDS16((const char*)(A + (size_t)(row0 + r) * K + k0) + scb, ab + (i << 10));
      GLOAD_LDS16((const char*)(BT + (size_t)(col0 + r) * K + k0) + scb, bb + (i << 10));
    }
  };

  STAGE(0, 0);
  __syncthreads();

  int nt = K / 64;
  for (int t = 0; t < nt; ++t) {
    int cur = t & 1;
    if (t + 1 < nt) STAGE((t + 1) * 64, cur ^ 1);  // in flight under compute

    const char* Ac = (const char*)As[cur];
    const char* Bc = (const char*)Bs[cur];
    int rsw = (lr & 7) << 4;  // read-side XOR (row & 7 == lr & 7)
#pragma unroll
    for (int kc = 0; kc < 2; ++kc) {
      bf8_t av[4], bv[4];
#pragma unroll
      for (int mi = 0; mi < 4; ++mi) {
        int row = 64 * wr + 16 * mi + lr;
        av[mi] = *(const bf8_t*)(Ac + row * 128 + ((64 * kc + 16 * lhi) ^ rsw));
      }
#pragma unroll
      for (int ni = 0; ni < 4; ++ni) {
        int row = 64 * wc + 16 * ni + lr;
        bv[ni] = *(const bf8_t*)(Bc + row * 128 + ((64 * kc + 16 * lhi) ^ rsw));
      }
#pragma unroll
      for (int mi = 0; mi < 4; ++mi)
#pragma unroll
        for (int ni = 0; ni < 4; ++ni)
          acc[mi][ni] = __builtin_amdgcn_mfma_f32_16x16x32_bf16(av[mi], bv[ni], acc[mi][ni], 0, 0, 0);
    }
    __syncthreads();  // drains this iter's STAGE; publishes buf^1
  }

#pragma unroll
  for (int mi = 0; mi < 4; ++mi)
#pragma unroll
    for (int ni = 0; ni < 4; ++ni)
#pragma unroll
      for (int r = 0; r < 4; ++r) {
        int row = row0 + 64 * wr + 16 * mi + 4 * lhi + r;
        int col = col0 + 64 * wc + 16 * ni + lr;
        float v = acc[mi][ni][r];
        if (MODE == 0) {
          int which = col / 768;
          int cc2 = col - which * 768;
          int h = cc2 >> 6, dh = cc2 & 63;
          int b = row >> 11, n = row & 2047;
          size_t dst = (((size_t)(b * H_ + h)) * N_ + n) * DH_ + dh;
          short bv2 = f2b(v);
          if (which == 0) Qb[dst] = bv2;
          else if (which == 1) Kb[dst] = bv2;
          else Vb[dst] = bv2;
        } else {
          Cout[(size_t)row * ldc + col] = v;
        }
      }
}

// ---------------- per-batch valid-index list (order-preserving scan) ----------------
__global__ __launch_bounds__(256) void k_maskidx(const int* __restrict__ xmask,
                                                 int* __restrict__ idx,
                                                 int* __restrict__ cnt) {
  int b = blockIdx.x, t = threadIdx.x;
  const int* mp = xmask + b * N_;
  int loc[8], c = 0;
#pragma unroll
  for (int j = 0; j < 8; ++j) {
    int n = t * 8 + j;
    if (mp[n]) loc[c++] = n;
  }
  __shared__ int sc[256];
  sc[t] = c;
  __syncthreads();
  for (int off = 1; off < 256; off <<= 1) {
    int v = (t >= off) ? sc[t - off] : 0;
    __syncthreads();
    sc[t] += v;
    __syncthreads();
  }
  int base = sc[t] - c;
  int* op = idx + b * N_;
  for (int j = 0; j < c; ++j) op[base + j] = loc[j];
  if (t == 255) cnt[b] = sc[255];
}

// ---------------- Vmean stage A: per-(bh,chunk) partial sums (deterministic) ----------------
__global__ __launch_bounds__(256) void k_vmeanA(const short* __restrict__ Vb,
                                                float* __restrict__ part) {
  int bh = blockIdx.y, ch = blockIdx.x, t = threadIdx.x;
  int rg = t >> 3, cg = t & 7;
  const short* vp = Vb + ((size_t)bh * N_ + ch * 256 + rg) * DH_ + cg * 8;
  float a[8] = {0, 0, 0, 0, 0, 0, 0, 0};
#pragma unroll
  for (int k = 0; k < 8; ++k) {
    bf8_t v = *(const bf8_t*)(vp + (size_t)32 * k * DH_);
#pragma unroll
    for (int e = 0; e < 8; ++e) a[e] += b2f(v[e]);
  }
  __shared__ float red[8][32][8];
#pragma unroll
  for (int e = 0; e < 8; ++e) red[cg][rg][e] = a[e];
  __syncthreads();
  if (t < 64) {
    int g = t >> 3, j = t & 7;
    float s = 0;
#pragma unroll
    for (int i = 0; i < 32; ++i) s += red[g][i][j];
    part[((size_t)bh * 8 + ch) * 64 + g * 8 + j] = s;
  }
}

// ---------------- Vmean stage B: reduce 8 partials ----------------
__global__ __launch_bounds__(256) void k_vmeanB(const float* __restrict__ part,
                                                float* __restrict__ Vmean) {
  int i = blockIdx.x * 256 + threadIdx.x;
  if (i >= 48 * 64) return;
  int bh = i >> 6, dh = i & 63;
  float s = 0;
#pragma unroll
  for (int c = 0; c < 8; ++c) s += part[((size_t)bh * 8 + c) * 64 + dh];
  Vmean[i] = s * (1.f / 2048.f);
}

// -------- gather K,V by idx into compacted Kc[bh][j][dh], Vtc[bh][dh][j] --------
__global__ __launch_bounds__(256) void k_gather(const short* __restrict__ Kb,
                                                const short* __restrict__ Vb,
                                                const int* __restrict__ idx,
                                                const int* __restrict__ cnt,
                                                short* __restrict__ Kc,
                                                short* __restrict__ Vtc) {
  int bh = blockIdx.y, b = bh / H_;
  int j0 = blockIdx.x * 64;
  int cn = cnt[b];
  int cp = (cn + 63) & ~63;
  if (j0 >= cp) return;
  int t = threadIdx.x;
  __shared__ int sidx[64];
  __shared__ short vt[64][72];
  if (t < 64) sidx[t] = (j0 + t < cn) ? idx[b * N_ + j0 + t] : -1;
  __syncthreads();
  int r = t >> 2, c16 = (t & 3) * 16;
  int src = sidx[r];
  const bf8_t zz = {0, 0, 0, 0, 0, 0, 0, 0};
#pragma unroll
  for (int u = 0; u < 2; ++u) {
    bf8_t kv = (src >= 0) ? *(const bf8_t*)(Kb + ((size_t)bh * N_ + src) * DH_ + c16 + u * 8) : zz;
    bf8_t vv = (src >= 0) ? *(const bf8_t*)(Vb + ((size_t)bh * N_ + src) * DH_ + c16 + u * 8) : zz;
    *(bf8_t*)(Kc + ((size_t)bh * N_ + j0 + r) * DH_ + c16 + u * 8) = kv;
    *(bf8_t*)(&vt[r][c16 + u * 8]) = vv;
  }
  __syncthreads();
  int dh = t >> 2;
#pragma unroll
  for (int u = 0; u < 2; ++u) {
    bf8_t ov;
#pragma unroll
    for (int e = 0; e < 8; ++e) ov[e] = vt[c16 + u * 8 + e][dh];
    *(bf8_t*)(Vtc + ((size_t)bh * DH_ + dh) * N_ + j0 + c16 + u * 8) = ov;
  }
}

// -------- fill masked-q rows of Ao with Vmean (uniform-softmax result) --------
__global__ __launch_bounds__(256) void k_fill(const int* __restrict__ xmask,
                                              const float* __restrict__ Vmean,
                                              short* __restrict__ Ao) {
  int b = blockIdx.y;
  int n = blockIdx.x * 32 + (threadIdx.x >> 3);
  int cg = threadIdx.x & 7;
  if (xmask[b * N_ + n]) return;
#pragma unroll
  for (int k = 0; k < 12; ++k) {
    int col = cg * 8 + k * 64;
    int h = col >> 6, dh = col & 63;
    const float* vp = Vmean + ((size_t)b * H_ + h) * 64 + dh;
    bf8_t ov;
#pragma unroll
    for (int e = 0; e < 8; ++e) ov[e] = f2b(vp[e]);
    *(bf8_t*)(Ao + ((size_t)b * N_ + n) * D_ + col) = ov;
  }
}

// -------- flash attention on COMPACTED q/k (swapped-QK^T 32x32) --------
__global__ __launch_bounds__(256, 3) void k_attn(const short* __restrict__ Q,
                                                 const short* __restrict__ Kcg,
                                                 const short* __restrict__ Vtcg,
                                                 const int* __restrict__ idx,
                                                 const int* __restrict__ cnt,
                                                 short* __restrict__ Aout) {
  int bh = blockIdx.y;
  int b = bh / H_, h = bh - b * H_;
  int cn = cnt[b];
  int nqt = (cn + 127) >> 7;
  if ((int)blockIdx.x >= nqt) return;  // block-uniform exit
  int nkt = (cn + 63) >> 6;
  const short* Qp = Q + (size_t)bh * N_ * DH_;
  const short* Kp = Kcg + (size_t)bh * N_ * DH_;
  const short* Vp = Vtcg + (size_t)bh * DH_ * N_;
  const int* ip = idx + b * N_;
  int q0 = blockIdx.x * 128;
  int tid = threadIdx.x, lane = tid & 63, w = tid >> 6;
  int lq = lane & 31, hi = lane >> 5;

  __shared__ char smem[32768];

  int qrow = q0 + 32 * w + lq;
  int qn = ip[qrow < cn ? qrow : cn - 1];  // clamp tail (stores guarded later)

  bf8_t qf[4];
#pragma unroll
  for (int kc = 0; kc < 4; ++kc)
    qf[kc] = *(const bf8_t*)(Qp + (size_t)qn * DH_ + 16 * kc + 8 * hi);

  short NEGBIG = f2b(-1e30f);
  bf8_t qbf = {hi ? (short)0 : (short)0x3F80, 0, 0, 0, 0, 0, 0, 0};  // bias B (1.0)

  f16v acco[2];
#pragma unroll
  for (int i = 0; i < 16; ++i) { acco[0][i] = 0.f; acco[1][i] = 0.f; }
  float m = -1e29f, lsum = 0.f;

  auto STAGE = [&](int key0, int buf) {
    char* kb_ = smem + buf * 16384;
    char* vb_ = kb_ + 8192;
    int row = tid >> 3;
    int cb = (tid & 7) * 16;
    char* lk = kb_ + ((tid >> 6) << 10);
    char* lv = vb_ + ((tid >> 6) << 10);
#pragma unroll
    for (int rr = 0; rr < 2; ++rr) {
      int r2 = row + rr * 32;
      int sw = cb ^ ((r2 & 7) << 4);
      GLOAD_LDS16((const char*)(Kp + (size_t)(key0 + r2) * DH_) + sw, lk + rr * 4096);
      GLOAD_LDS16((const char*)(Vp + (size_t)r2 * N_ + key0) + sw, lv + rr * 4096);
    }
  };

  STAGE(0, 0);
  __syncthreads();

  for (int kt = 0; kt < nkt; ++kt) {
    int cur = kt & 1;
    if (kt + 1 < nkt) STAGE((kt + 1) * 64, cur ^ 1);

    const char* kbase = smem + cur * 16384;
    const char* vbase = kbase + 8192;
    int key0 = kt * 64;

    f16v accs[2];
#pragma unroll
    for (int i = 0; i < 16; ++i) { accs[0][i] = 0.f; accs[1][i] = 0.f; }
    int swz = (lq & 7) << 4;
    __builtin_amdgcn_s_setprio(1);
#pragma unroll
    for (int kc = 0; kc < 4; ++kc) {
      int colb = (32 * kc + 16 * hi) ^ swz;
      bf8_t k0 = *(const bf8_t*)(kbase + lq * 128 + colb);
      bf8_t k1 = *(const bf8_t*)(kbase + (32 + lq) * 128 + colb);
      accs[0] = __builtin_amdgcn_mfma_f32_32x32x16_bf16(k0, qf[kc], accs[0], 0, 0, 0);
      accs[1] = __builtin_amdgcn_mfma_f32_32x32x16_bf16(k1, qf[kc], accs[1], 0, 0, 0);
    }
    __builtin_amdgcn_s_setprio(0);
    if (key0 + 64 > cn) {  // tail guard: keys j >= cn get -1e30 bias
      bf8_t bf0 = {(hi || key0 + lq < cn) ? (short)0 : NEGBIG, 0, 0, 0, 0, 0, 0, 0};
      bf8_t bf1 = {(hi || key0 + 32 + lq < cn) ? (short)0 : NEGBIG, 0, 0, 0, 0, 0, 0, 0};
      accs[0] = __builtin_amdgcn_mfma_f32_32x32x16_bf16(bf0, qbf, accs[0], 0, 0, 0);
      accs[1] = __builtin_amdgcn_mfma_f32_32x32x16_bf16(bf1, qbf, accs[1], 0, 0, 0);
    }

    float mx = max3f(accs[0][0], accs[0][1], accs[0][2]);
#pragma unroll
    for (int i = 3; i < 15; i += 2) mx = max3f(mx, accs[0][i], accs[0][i + 1]);
    mx = max3f(mx, accs[0][15], accs[1][0]);
#pragma unroll
    for (int i = 1; i < 15; i += 2) mx = max3f(mx, accs[1][i], accs[1][i + 1]);
    mx = fmaxf(mx, accs[1][15]);
    mx = fmaxf(mx, __shfl_xor(mx, 32));
    if (!__all(mx <= m + 8.f)) {
      float mnew = fmaxf(m, mx);
      float sc = __builtin_amdgcn_exp2f(m - mnew);
      m = mnew;
      lsum *= sc;
#pragma unroll
      for (int i = 0; i < 16; ++i) { acco[0][i] *= sc; acco[1][i] *= sc; }
    }
    float psa[4] = {0.f, 0.f, 0.f, 0.f};
#pragma unroll
    for (int kb2 = 0; kb2 < 2; ++kb2)
#pragma unroll
      for (int r = 0; r < 16; ++r) {
        float p = __builtin_amdgcn_exp2f(accs[kb2][r] - m);
        accs[kb2][r] = p;
        psa[r & 3] += p;
      }
    float ps = (psa[0] + psa[1]) + (psa[2] + psa[3]);
    ps += __shfl_xor(ps, 32);
    lsum += ps;

    __builtin_amdgcn_s_setprio(1);
#pragma unroll
    for (int kc = 0; kc < 4; ++kc) {
      int kb2 = kc >> 1, rb = (kc & 1) * 8;
      unsigned a_ = cvtpk(accs[kb2][rb + 0], accs[kb2][rb + 1]);
      unsigned b_ = cvtpk(accs[kb2][rb + 4], accs[kb2][rb + 5]);
      unsigned c_ = cvtpk(accs[kb2][rb + 2], accs[kb2][rb + 3]);
      unsigned d_ = cvtpk(accs[kb2][rb + 6], accs[kb2][rb + 7]);
      plswap(a_, b_);
      plswap(c_, d_);
      union { i4_t i; bf8_t v; } pu;
      pu.i = (i4_t){(int)a_, (int)c_, (int)b_, (int)d_};
      int colb = (32 * kc + 16 * hi) ^ swz;
      bf8_t v0 = *(const bf8_t*)(vbase + lq * 128 + colb);
      bf8_t v1 = *(const bf8_t*)(vbase + (32 + lq) * 128 + colb);
      acco[0] = __builtin_amdgcn_mfma_f32_32x32x16_bf16(v0, pu.v, acco[0], 0, 0, 0);
      acco[1] = __builtin_amdgcn_mfma_f32_32x32x16_bf16(v1, pu.v, acco[1], 0, 0, 0);
    }
    __builtin_amdgcn_s_setprio(0);

    __syncthreads();
  }
  __syncthreads();  // all waves done with K/V buffers before Os reuse

  float inv = 1.f / lsum;
  unsigned* Os = (unsigned*)smem + w * 1152;
#pragma unroll
  for (int dhb = 0; dhb < 2; ++dhb)
#pragma unroll
    for (int r = 0; r < 16; r += 2) {
      unsigned pk = cvtpk(acco[dhb][r] * inv, acco[dhb][r + 1] * inv);
      int colu = 16 * dhb + ((r & 3) >> 1) + 4 * (r >> 2) + 2 * hi;
      Os[lq * 36 + colu] = pk;
    }
#pragma unroll
  for (int it = 0; it < 4; ++it) {
    int q = (lane >> 3) + 8 * it;
    int qr2 = q0 + 32 * w + q;
    if (qr2 < cn) {
      int n = ip[qr2];
      i4_t vv = *(const i4_t*)(Os + q * 36 + 4 * (lane & 7));
      union { i4_t i; bf8_t s; } u2;
      u2.i = vv;
      size_t off = ((size_t)b * N_ + n) * D_ + h * DH_ + 8 * (lane & 7);
      *(bf8_t*)(Aout + off) = u2.s;
    }
  }
}

extern "C" void kernel_launch(void* const* d_in, const int* in_sizes, int n_in,
                              void* d_out, int out_size, void* d_ws, size_t ws_size,
                              hipStream_t stream) {
  (void)in_sizes; (void)n_in; (void)out_size; (void)ws_size;
  const float* x  = (const float*)d_in[0];
  const int*   xm = (const int*)d_in[1];
  const float* Wq = (const float*)d_in[2];
  const float* Wk = (const float*)d_in[3];
  const float* Wv = (const float*)d_in[4];
  const float* Wo = (const float*)d_in[5];
  float* out = (float*)d_out;
  char* ws = (char*)d_ws;

  short* x_bf  = (short*)(ws + 0);         // x_bf during QKV-GEMM...
  short* Ao    = (short*)(ws + 0);         // ...then reused as attn output
  short* WqkvT = (short*)(ws + 12582912);
  int*   idxb  = (int*)(ws + 12582912);    // aux overlays WqkvT after gemm<0>
  int*   cntb  = (int*)(ws + 12615680);
  float* part  = (float*)(ws + 12615744);
  float* Vmean = (float*)(ws + 12714048);
  short* WoT   = (short*)(ws + 16121856);
  short* Qb    = (short*)(ws + 17301504);
  short* Kb    = (short*)(ws + 29884416);
  short* Vb    = (short*)(ws + 42467328);
  short* Kc    = (short*)(ws + 55050240);
  short* Vtc   = (short*)(ws + 67633152);

  k_convx<<<3072, 256, 0, stream>>>(x, x_bf);
  k_wtrans<<<dim3(12, 12, 4), 256, 0, stream>>>(Wq, Wk, Wv, Wo, WqkvT, WoT);
  k_gemm<0><<<dim3(18, 64), 256, 0, stream>>>(x_bf, WqkvT, 768, Qb, Kb, Vb, nullptr, 0);
  k_maskidx<<<4, 256, 0, stream>>>(xm, idxb, cntb);
  k_vmeanA<<<dim3(8, 48), 256, 0, stream>>>(Vb, part);
  k_vmeanB<<<12, 256, 0, stream>>>(part, Vmean);
  k_gather<<<dim3(32, 48), 256, 0, stream>>>(Kb, Vb, idxb, cntb, Kc, Vtc);
  k_attn<<<dim3(16, 48), 256, 0, stream>>>(Qb, Kc, Vtc, idxb, cntb, Ao);
  k_fill<<<dim3(64, 4), 256, 0, stream>>>(xm, Vmean, Ao);
  k_gemm<1><<<dim3(6, 64), 256, 0, stream>>>(Ao, WoT, 768, nullptr, nullptr, nullptr, out, 768);
}